// Round 1
// 802.463 us; speedup vs baseline: 1.1654x; 1.1654x over previous
//
#include <hip/hip_runtime.h>
#include <hip/hip_bf16.h>

#define N_NODES  50000
#define N_EDGES  400000
#define E_TOT    450000   // edges + self loops
#define N_GRAPHS 128
#define D_IN     768
#define D_HID    256

typedef __hip_bfloat16 bf16;
typedef __attribute__((ext_vector_type(8))) short short8;
typedef __attribute__((ext_vector_type(4))) float f32x4;

__device__ __forceinline__ float b2f(bf16 v) { return __bfloat162float(v); }
__device__ __forceinline__ float us2f(unsigned short u) { return __uint_as_float((unsigned)u << 16); }
__device__ __forceinline__ int clampN(int v) { return min(max(v, 0), N_NODES - 1); }
// fp32 -> bf16 bits (RNE), as short for MFMA fragments
__device__ __forceinline__ short f2bs(float f) {
  unsigned u = __float_as_uint(f);
  return (short)((u + 0x7FFFu + ((u >> 16) & 1u)) >> 16);
}

__device__ __forceinline__ float waveReduceSum(float v) {
#pragma unroll
  for (int o = 32; o > 0; o >>= 1) v += __shfl_down(v, o);
  return v;
}

__device__ __forceinline__ float blockReduce256(float v, volatile float* buf4) {
  int lane = threadIdx.x & 63, wid = threadIdx.x >> 6;
  v = waveReduceSum(v);
  if (lane == 0) buf4[wid] = v;
  __syncthreads();
  float s = buf4[0] + buf4[1] + buf4[2] + buf4[3];
  __syncthreads();
  return s;
}

// ---------------- index dtype detection + normalization ----------------
__global__ __launch_bounds__(256) void detect_idx_kernel(
    const int* __restrict__ edge32, int* __restrict__ flagNZ) {
  int t = threadIdx.x;
  int nz = 0;
#pragma unroll
  for (int i = 0; i < 4; ++i) {
    int idx = 2 * (t + i * 256) + 1;
    if (edge32[idx] != 0) nz = 1;
  }
  if (nz) atomicOr(flagNZ, 1);
}

__global__ __launch_bounds__(256) void normalize_idx_kernel(
    const void* __restrict__ edge, const void* __restrict__ nbin,
    const int* __restrict__ flagNZ,
    int* __restrict__ src32, int* __restrict__ dst32, int* __restrict__ nb32) {
  bool is64 = (*flagNZ == 0);
  long i = (long)blockIdx.x * 256 + threadIdx.x;
  const int*       e32 = (const int*)edge;
  const long long* e64 = (const long long*)edge;
  const int*       n32 = (const int*)nbin;
  const long long* n64 = (const long long*)nbin;
  if (i < N_EDGES) {
    src32[i] = clampN(is64 ? (int)e64[i] : e32[i]);
    dst32[i] = clampN(is64 ? (int)e64[N_EDGES + i] : e32[N_EDGES + i]);
  }
  long j = i - N_EDGES;
  if (j >= 0 && j < N_NODES)
    nb32[j] = min(max(is64 ? (int)n64[j] : n32[j], 0), N_GRAPHS - 1);
}

// ---------------- CSR build: histogram -> hierarchical scan -> scatter ----------------
__global__ __launch_bounds__(256) void hist_kernel(
    const int* __restrict__ dst, int* __restrict__ deg) {
  int i = blockIdx.x * 256 + threadIdx.x;
  if (i >= E_TOT) return;
  int d = (i < N_EDGES) ? dst[i] : (i - N_EDGES);
  atomicAdd(&deg[d], 1);
}

// Hierarchical scan (replaces the single-block 196-iteration serial scan that
// was 143 us at 0.046% occupancy):
//   stage 1: each block scans SCAN_BLK elems locally, emits block sum
//   stage 2: one block exclusive-scans the 49 block sums
//   stage 3: add block offsets, emit rowptr / pos
#define SCAN_VPT 4
#define SCAN_BLK (256 * SCAN_VPT)                       // 1024 elems / block
#define SCAN_NB  ((N_NODES + SCAN_BLK - 1) / SCAN_BLK)  // 49 blocks

__global__ __launch_bounds__(256) void scan_local_kernel(
    const int* __restrict__ deg, int* __restrict__ incl, int* __restrict__ blockSums) {
  __shared__ int wsum[4];
  int lane = threadIdx.x & 63, wid = threadIdx.x >> 6;
  int tbase = blockIdx.x * SCAN_BLK + threadIdx.x * SCAN_VPT;
  int v[SCAN_VPT];
  int s = 0;
#pragma unroll
  for (int j = 0; j < SCAN_VPT; ++j) {
    int i = tbase + j;
    v[j] = (i < N_NODES) ? deg[i] : 0;
    s += v[j];
  }
  int sc = s;
#pragma unroll
  for (int o = 1; o < 64; o <<= 1) {
    int t = __shfl_up(sc, o);
    if (lane >= o) sc += t;
  }
  if (lane == 63) wsum[wid] = sc;
  __syncthreads();
  int woff = 0;
  for (int w = 0; w < wid; ++w) woff += wsum[w];
  int run = woff + sc - s;   // exclusive prefix for this thread within block
#pragma unroll
  for (int j = 0; j < SCAN_VPT; ++j) {
    run += v[j];
    int i = tbase + j;
    if (i < N_NODES) incl[i] = run;   // block-local inclusive scan
  }
  if (threadIdx.x == 255)
    blockSums[blockIdx.x] = woff + sc;  // block total
}

__global__ __launch_bounds__(256) void scan_spine_kernel(int* __restrict__ bs) {
  __shared__ int wsum[4];
  int lane = threadIdx.x & 63, wid = threadIdx.x >> 6;
  int v = (threadIdx.x < SCAN_NB) ? bs[threadIdx.x] : 0;
  int sc = v;
#pragma unroll
  for (int o = 1; o < 64; o <<= 1) {
    int t = __shfl_up(sc, o);
    if (lane >= o) sc += t;
  }
  if (lane == 63) wsum[wid] = sc;
  __syncthreads();
  int woff = 0;
  for (int w = 0; w < wid; ++w) woff += wsum[w];
  if (threadIdx.x < SCAN_NB) bs[threadIdx.x] = woff + sc - v;  // exclusive
}

__global__ __launch_bounds__(256) void scan_add_kernel(
    const int* __restrict__ deg, const int* __restrict__ incl,
    const int* __restrict__ blockOffs,
    int* __restrict__ rowptr, int* __restrict__ pos) {
  int i = blockIdx.x * 256 + threadIdx.x;
  if (i >= N_NODES) return;
  int ic = incl[i] + blockOffs[i / SCAN_BLK];
  rowptr[i + 1] = ic;
  pos[i] = ic - deg[i];
  if (i == 0) rowptr[0] = 0;
}

__global__ __launch_bounds__(256) void scatter_kernel(
    const int* __restrict__ src, const int* __restrict__ dst,
    int* __restrict__ pos, int* __restrict__ srcS) {
  int i = blockIdx.x * 256 + threadIdx.x;
  if (i >= E_TOT) return;
  int s, d;
  if (i < N_EDGES) { s = src[i]; d = dst[i]; } else { s = d = i - N_EDGES; }
  int j = atomicAdd(&pos[d], 1);
  srcS[j] = s;
}

// ---------------- weight transpose + bf16 convert: WT[n][k] = bf16(W[k][n]) ----------------
__global__ __launch_bounds__(256) void convert_wt_kernel(
    const float* __restrict__ W, short* __restrict__ WT, int K, int N) {
  int i = blockIdx.x * 256 + threadIdx.x;
  if (i >= K * N) return;
  int n = i / K, k = i - n * K;
  WT[i] = f2bs(W[(size_t)k * N + n]);
}

// ---------------- relevance: rel[n] = cos(claim[batch[n]], x[n]) ----------------
__global__ __launch_bounds__(256) void rel_kernel(
    const float* __restrict__ x, const float* __restrict__ claim,
    const int* __restrict__ nb, float* __restrict__ rel) {
  __shared__ float buf[4];
  int n = blockIdx.x;
  int g = nb[n];
  const float* xr = x + (size_t)n * D_IN;
  const float* cr = claim + (size_t)g * D_IN;
  float dot = 0.f, nx = 0.f, nc = 0.f;
#pragma unroll
  for (int i = 0; i < 3; ++i) {
    int d = threadIdx.x + i * 256;
    float xv = xr[d], cv = cr[d];
    dot += xv * cv; nx += xv * xv; nc += cv * cv;
  }
  dot = blockReduce256(dot, buf);
  nx  = blockReduce256(nx, buf);
  nc  = blockReduce256(nc, buf);
  if (threadIdx.x == 0)
    rel[n] = dot / fmaxf(sqrtf(nx) * sqrtf(nc), 1e-8f);
}

// ---------------- MFMA GEMM: C[M,256] = epi(A[M,K]) @ B[K,256], C bf16 ----------------
// Tile 64x256 per block (4 waves, wave = 16 rows x full N). A staged fp32->bf16 with
// fused epilogue: EPI=0 row-scale (rel); EPI=1 per-col BN scale/shift + ReLU.
// Layouts (HW-verified): A-frag A[m=lane&15][k=quad*8+j]; B-frag B[k=quad*8+j][n=lane&15]
// (from W^T, contiguous k); C/D col=lane&15, row=quad*4+reg.
#define BK 32
template <int EPI>
__global__ __launch_bounds__(256) void mfma_gemm_kernel(
    const float* __restrict__ A, const short* __restrict__ BT,
    const float* __restrict__ rowScale,
    const float* __restrict__ cscale, const float* __restrict__ cshift,
    bf16* __restrict__ C, int M, int K) {
  __shared__ short As[64][BK + 8];    // stride 40 shorts = 80B (16B-aligned rows)
  __shared__ short Bs[256][BK + 8];
  int tid = threadIdx.x;
  int wave = tid >> 6, lane = tid & 63;
  int quad = lane >> 4, l16 = lane & 15;
  int mBase = blockIdx.x * 64;

  f32x4 acc[16] = {};

  int ar = tid >> 2;            // A stage: row 0..63
  int ak = (tid & 3) * 8;       // k offset 0,8,16,24
  int arow = mBase + ar;
  float rm = 1.f;
  if (EPI == 0 && arow < M) rm = rowScale[arow];

  for (int k0 = 0; k0 < K; k0 += BK) {
    // ---- stage A (fp32 -> epi -> bf16) ----
    float av[8];
    if (arow < M) {
      const f32x4* ap = (const f32x4*)(A + (size_t)arow * K + k0 + ak);
      f32x4 v0 = ap[0], v1 = ap[1];
      av[0]=v0.x; av[1]=v0.y; av[2]=v0.z; av[3]=v0.w;
      av[4]=v1.x; av[5]=v1.y; av[6]=v1.z; av[7]=v1.w;
      if (EPI == 0) {
#pragma unroll
        for (int j = 0; j < 8; ++j) av[j] *= rm;
      } else {
#pragma unroll
        for (int j = 0; j < 8; ++j) {
          int kk = k0 + ak + j;
          av[j] = fmaxf(av[j] * cscale[kk] + cshift[kk], 0.f);
        }
      }
    } else {
#pragma unroll
      for (int j = 0; j < 8; ++j) av[j] = 0.f;
    }
    short8 a8;
#pragma unroll
    for (int j = 0; j < 8; ++j) a8[j] = f2bs(av[j]);
    *(short8*)&As[ar][ak] = a8;
    // ---- stage B (bf16 W^T row per thread) ----
    {
      const short8* bp = (const short8*)(BT + (size_t)tid * K + k0);
#pragma unroll
      for (int j = 0; j < 4; ++j)
        *(short8*)&Bs[tid][j * 8] = bp[j];
    }
    __syncthreads();
    // ---- compute ----
    short8 af = *(short8*)&As[wave * 16 + l16][quad * 8];
#pragma unroll
    for (int nt = 0; nt < 16; ++nt) {
      short8 bf = *(short8*)&Bs[nt * 16 + l16][quad * 8];
      acc[nt] = __builtin_amdgcn_mfma_f32_16x16x32_bf16(af, bf, acc[nt], 0, 0, 0);
    }
    __syncthreads();
  }
  // ---- epilogue store ----
#pragma unroll
  for (int nt = 0; nt < 16; ++nt) {
#pragma unroll
    for (int r = 0; r < 4; ++r) {
      int m = mBase + wave * 16 + quad * 4 + r;
      if (m < M)
        C[(size_t)m * D_HID + nt * 16 + l16] = __float2bfloat16(acc[nt][r]);
    }
  }
}

// ---------------- per-node attention logits: alpha = h @ a ----------------
__global__ __launch_bounds__(256) void alpha_kernel(
    const bf16* __restrict__ h, const float* __restrict__ a_src,
    const float* __restrict__ a_dst, float* __restrict__ as_, float* __restrict__ ad_) {
  __shared__ float buf[4];
  int n = blockIdx.x;
  float hv = b2f(h[(size_t)n * D_HID + threadIdx.x]);
  float s = hv * a_src[threadIdx.x];
  float d = hv * a_dst[threadIdx.x];
  s = blockReduce256(s, buf);
  d = blockReduce256(d, buf);
  if (threadIdx.x == 0) { as_[n] = s; ad_[n] = d; }
}

// ---------------- fused GAT softmax + aggregate: one wave per dst node ----------------
__global__ __launch_bounds__(256) void gat_agg_kernel(
    const int* __restrict__ rowptr, const int* __restrict__ srcS,
    const float* __restrict__ as_, const float* __restrict__ ad_,
    const bf16* __restrict__ h, float* __restrict__ agg) {
  int wid = threadIdx.x >> 6, lane = threadIdx.x & 63;
  int n = blockIdx.x * 4 + wid;
  if (n >= N_NODES) return;
  int start = rowptr[n], end = rowptr[n + 1];
  float adn = ad_[n];
  float m = -1e30f;
  for (int j0 = start; j0 < end; j0 += 64) {
    int j = j0 + lane;
    if (j < end) {
      float e = as_[srcS[j]] + adn;
      e = e > 0.f ? e : 0.2f * e;
      m = fmaxf(m, e);
    }
  }
#pragma unroll
  for (int o = 32; o > 0; o >>= 1) m = fmaxf(m, __shfl_xor(m, o));
  float ssum = 0.f;
  for (int j0 = start; j0 < end; j0 += 64) {
    int j = j0 + lane;
    if (j < end) {
      float e = as_[srcS[j]] + adn;
      e = e > 0.f ? e : 0.2f * e;
      ssum += __expf(e - m);
    }
  }
#pragma unroll
  for (int o = 32; o > 0; o >>= 1) ssum += __shfl_xor(ssum, o);
  float inv = 1.f / ssum;
  float a0 = 0.f, a1 = 0.f, a2 = 0.f, a3 = 0.f;
  const unsigned short* hp = (const unsigned short*)h;
  for (int j = start; j < end; ++j) {
    int s = srcS[j];
    float e = as_[s] + adn;
    e = e > 0.f ? e : 0.2f * e;
    float attn = __expf(e - m) * inv;
    const ushort4 hv = *(const ushort4*)(hp + (size_t)s * D_HID + lane * 4);
    a0 += us2f(hv.x) * attn;
    a1 += us2f(hv.y) * attn;
    a2 += us2f(hv.z) * attn;
    a3 += us2f(hv.w) * attn;
  }
  float4 o4 = {a0, a1, a2, a3};
  *(float4*)(agg + (size_t)n * D_HID + lane * 4) = o4;
}

// ---------------- batch norm (training stats) ----------------
__global__ __launch_bounds__(256) void bn_stats_kernel(
    const float* __restrict__ h, float* __restrict__ sums, float* __restrict__ sumsq) {
  int col = threadIdx.x;
  float s = 0.f, q = 0.f;
  for (int r = blockIdx.x; r < N_NODES; r += gridDim.x) {
    float v = h[(size_t)r * D_HID + col];
    s += v; q += v * v;
  }
  atomicAdd(&sums[col], s);
  atomicAdd(&sumsq[col], q);
}

__global__ __launch_bounds__(256) void bn_finalize_kernel(
    const float* __restrict__ sums, const float* __restrict__ sumsq,
    const float* __restrict__ gamma, const float* __restrict__ beta,
    float* __restrict__ scale, float* __restrict__ shift) {
  int c = threadIdx.x;
  float mu = sums[c] / N_NODES;
  float var = fmaxf(sumsq[c] / N_NODES - mu * mu, 0.f);
  float sc = gamma[c] * rsqrtf(var + 1e-5f);
  scale[c] = sc;
  shift[c] = beta[c] - mu * sc;
}

// ---------------- mean pool (node_batch sorted) + b2 + relu ----------------
__global__ __launch_bounds__(256) void pool_kernel(
    const float* __restrict__ h, const float* __restrict__ bias2,
    const int* __restrict__ nb, float* __restrict__ pooled) {
  int col = threadIdx.x;
  float bias = bias2[col];
  int chunk = (N_NODES + gridDim.x - 1) / gridDim.x;
  int r0 = blockIdx.x * chunk;
  int r1 = min(N_NODES, r0 + chunk);
  float acc = 0.f; int cur = -1;
  for (int r = r0; r < r1; ++r) {
    int g = nb[r];
    if (g != cur) {
      if (cur >= 0) atomicAdd(&pooled[(size_t)cur * D_HID + col], acc);
      acc = 0.f; cur = g;
    }
    acc += fmaxf(h[(size_t)r * D_HID + col] + bias, 0.f);
  }
  if (cur >= 0) atomicAdd(&pooled[(size_t)cur * D_HID + col], acc);
}

__global__ __launch_bounds__(256) void count_kernel(
    const int* __restrict__ nb, float* __restrict__ counts) {
  __shared__ int cnt[N_GRAPHS];
  for (int i = threadIdx.x; i < N_GRAPHS; i += 256) cnt[i] = 0;
  __syncthreads();
  int n = blockIdx.x * 256 + threadIdx.x;
  if (n < N_NODES) atomicAdd(&cnt[nb[n]], 1);
  __syncthreads();
  for (int i = threadIdx.x; i < N_GRAPHS; i += 256)
    if (cnt[i]) atomicAdd(&counts[i], (float)cnt[i]);
}

// ---------------- classifier (OUTPUT FP32) ----------------
__global__ __launch_bounds__(256) void clf_kernel(
    const float* __restrict__ pooled, const float* __restrict__ counts,
    const float* __restrict__ claim, const float* __restrict__ clfW,
    const float* __restrict__ clfb, float* __restrict__ out) {
  __shared__ float buf[4];
  int g = blockIdx.x;
  float inv = 1.f / fmaxf(counts[g], 1.f);
  float p = 0.f;
  for (int d = threadIdx.x; d < (D_HID + D_IN); d += 256) {
    float w = clfW[d];
    float v = (d < D_HID) ? pooled[(size_t)g * D_HID + d] * inv
                          : claim[(size_t)g * D_IN + (d - D_HID)];
    p += v * w;
  }
  p = blockReduce256(p, buf);
  if (threadIdx.x == 0) out[g] = p + clfb[0];
}

extern "C" void kernel_launch(void* const* d_in, const int* in_sizes, int n_in,
                              void* d_out, int out_size, void* d_ws, size_t ws_size,
                              hipStream_t stream) {
  const float* claim = (const float*)d_in[0];
  const float* x     = (const float*)d_in[1];
  const void*  edge  = d_in[2];
  const void*  nbin  = d_in[3];
  const float* W1    = (const float*)d_in[4];
  const float* as1   = (const float*)d_in[5];
  const float* ad1   = (const float*)d_in[6];
  // d_in[7] = b1: cancels in BatchNorm
  const float* W2    = (const float*)d_in[8];
  const float* as2   = (const float*)d_in[9];
  const float* ad2   = (const float*)d_in[10];
  const float* b2v   = (const float*)d_in[11];
  const float* gamma = (const float*)d_in[12];
  const float* beta  = (const float*)d_in[13];
  const float* clfW  = (const float*)d_in[14];
  const float* clfb  = (const float*)d_in[15];
  float* out = (float*)d_out;

  char* wsb = (char*)d_ws;
  size_t off = 0;
  auto alloc = [&](size_t bytes) -> char* {
    char* p = wsb + off;
    off = (off + bytes + 255) & ~(size_t)255;
    return p;
  };
  int*   flagNZ = (int*)alloc(sizeof(int));
  int*   src32  = (int*)alloc((size_t)N_EDGES * sizeof(int));
  int*   dst32  = (int*)alloc((size_t)N_EDGES * sizeof(int));
  int*   nb32   = (int*)alloc((size_t)N_NODES * sizeof(int));
  int*   deg    = (int*)alloc((size_t)N_NODES * sizeof(int));
  int*   rowptr = (int*)alloc((size_t)(N_NODES + 1) * sizeof(int));
  int*   pos    = (int*)alloc((size_t)N_NODES * sizeof(int));
  int*   incl   = (int*)alloc((size_t)N_NODES * sizeof(int));
  int*   bsums  = (int*)alloc((size_t)SCAN_NB * sizeof(int));
  int*   srcS   = (int*)alloc((size_t)E_TOT * sizeof(int));
  short* W1T    = (short*)alloc((size_t)D_IN * D_HID * sizeof(short));
  short* W2T    = (short*)alloc((size_t)D_HID * D_HID * sizeof(short));
  float* rel    = (float*)alloc((size_t)N_NODES * sizeof(float));
  float* alphas = (float*)alloc((size_t)N_NODES * sizeof(float));
  float* alphad = (float*)alloc((size_t)N_NODES * sizeof(float));
  float* bnsums = (float*)alloc(D_HID * sizeof(float));
  float* bnsq   = (float*)alloc(D_HID * sizeof(float));
  float* bnscale= (float*)alloc(D_HID * sizeof(float));
  float* bnshift= (float*)alloc(D_HID * sizeof(float));
  float* pooled = (float*)alloc((size_t)N_GRAPHS * D_HID * sizeof(float));
  float* counts = (float*)alloc((size_t)N_GRAPHS * sizeof(float));
  float* agg    = (float*)alloc((size_t)N_NODES * D_HID * sizeof(float));
  bf16*  h      = (bf16*) alloc((size_t)N_NODES * D_HID * sizeof(bf16));

  // ---- index normalization + CSR build ----
  hipMemsetAsync(flagNZ, 0, sizeof(int), stream);
  detect_idx_kernel<<<1, 256, 0, stream>>>((const int*)edge, flagNZ);
  normalize_idx_kernel<<<(N_EDGES + N_NODES + 255) / 256, 256, 0, stream>>>(
      edge, nbin, flagNZ, src32, dst32, nb32);
  hipMemsetAsync(deg, 0, (size_t)N_NODES * sizeof(int), stream);
  int egrid = (E_TOT + 255) / 256;
  hist_kernel<<<egrid, 256, 0, stream>>>(dst32, deg);
  scan_local_kernel<<<SCAN_NB, 256, 0, stream>>>(deg, incl, bsums);
  scan_spine_kernel<<<1, 256, 0, stream>>>(bsums);
  scan_add_kernel<<<(N_NODES + 255) / 256, 256, 0, stream>>>(deg, incl, bsums, rowptr, pos);
  scatter_kernel<<<egrid, 256, 0, stream>>>(src32, dst32, pos, srcS);

  // ---- weights -> transposed bf16 (once) ----
  convert_wt_kernel<<<(D_IN * D_HID + 255) / 256, 256, 0, stream>>>(W1, W1T, D_IN, D_HID);
  convert_wt_kernel<<<(D_HID * D_HID + 255) / 256, 256, 0, stream>>>(W2, W2T, D_HID, D_HID);

  hipMemsetAsync(bnsums, 0, D_HID * 4, stream);
  hipMemsetAsync(bnsq, 0, D_HID * 4, stream);
  hipMemsetAsync(pooled, 0, (size_t)N_GRAPHS * D_HID * 4, stream);
  hipMemsetAsync(counts, 0, (size_t)N_GRAPHS * 4, stream);

  int gemmGrid = (N_NODES + 63) / 64;

  // ---- layer 1 ----
  rel_kernel<<<N_NODES, 256, 0, stream>>>(x, claim, nb32, rel);
  mfma_gemm_kernel<0><<<gemmGrid, 256, 0, stream>>>(x, W1T, rel, nullptr, nullptr, h, N_NODES, D_IN);
  alpha_kernel<<<N_NODES, 256, 0, stream>>>(h, as1, ad1, alphas, alphad);
  gat_agg_kernel<<<N_NODES / 4, 256, 0, stream>>>(rowptr, srcS, alphas, alphad, h, agg);

  bn_stats_kernel<<<256, 256, 0, stream>>>(agg, bnsums, bnsq);
  bn_finalize_kernel<<<1, 256, 0, stream>>>(bnsums, bnsq, gamma, beta, bnscale, bnshift);

  // ---- layer 2 (BN+ReLU fused into A-staging) ----
  mfma_gemm_kernel<1><<<gemmGrid, 256, 0, stream>>>(agg, W2T, nullptr, bnscale, bnshift, h, N_NODES, D_HID);
  alpha_kernel<<<N_NODES, 256, 0, stream>>>(h, as2, ad2, alphas, alphad);
  gat_agg_kernel<<<N_NODES / 4, 256, 0, stream>>>(rowptr, srcS, alphas, alphad, h, agg);

  // ---- pool + classifier ----
  pool_kernel<<<256, 256, 0, stream>>>(agg, b2v, nb32, pooled);
  count_kernel<<<(N_NODES + 255) / 256, 256, 0, stream>>>(nb32, counts);
  clf_kernel<<<N_GRAPHS, 256, 0, stream>>>(pooled, counts, claim, clfW, clfb, out);
}

// Round 2
// 690.474 us; speedup vs baseline: 1.3544x; 1.1622x over previous
//
#include <hip/hip_runtime.h>
#include <hip/hip_bf16.h>

#define N_NODES  50000
#define N_EDGES  400000
#define E_TOT    450000   // edges + self loops
#define N_GRAPHS 128
#define D_IN     768
#define D_HID    256

typedef __hip_bfloat16 bf16;
typedef __attribute__((ext_vector_type(8))) short short8;
typedef __attribute__((ext_vector_type(4))) short short4v;
typedef __attribute__((ext_vector_type(4))) float f32x4;

__device__ __forceinline__ float b2f(bf16 v) { return __bfloat162float(v); }
__device__ __forceinline__ float us2f(unsigned short u) { return __uint_as_float((unsigned)u << 16); }
__device__ __forceinline__ int clampN(int v) { return min(max(v, 0), N_NODES - 1); }
// fp32 -> bf16 bits (RNE), as short for MFMA fragments
__device__ __forceinline__ short f2bs(float f) {
  unsigned u = __float_as_uint(f);
  return (short)((u + 0x7FFFu + ((u >> 16) & 1u)) >> 16);
}

// async global->LDS, 16B per lane. LDS dest is wave-uniform base + lane*16.
__device__ __forceinline__ void gload_lds16(const void* g, void* l) {
  __builtin_amdgcn_global_load_lds(
      (const __attribute__((address_space(1))) void*)g,
      (__attribute__((address_space(3))) void*)l, 16, 0, 0);
}

__device__ __forceinline__ float waveReduceSum(float v) {
#pragma unroll
  for (int o = 32; o > 0; o >>= 1) v += __shfl_down(v, o);
  return v;
}

__device__ __forceinline__ float blockReduce256(float v, volatile float* buf4) {
  int lane = threadIdx.x & 63, wid = threadIdx.x >> 6;
  v = waveReduceSum(v);
  if (lane == 0) buf4[wid] = v;
  __syncthreads();
  float s = buf4[0] + buf4[1] + buf4[2] + buf4[3];
  __syncthreads();
  return s;
}

// ---------------- index dtype detection + normalization ----------------
__global__ __launch_bounds__(256) void detect_idx_kernel(
    const int* __restrict__ edge32, int* __restrict__ flagNZ) {
  int t = threadIdx.x;
  int nz = 0;
#pragma unroll
  for (int i = 0; i < 4; ++i) {
    int idx = 2 * (t + i * 256) + 1;
    if (edge32[idx] != 0) nz = 1;
  }
  if (nz) atomicOr(flagNZ, 1);
}

__global__ __launch_bounds__(256) void normalize_idx_kernel(
    const void* __restrict__ edge, const void* __restrict__ nbin,
    const int* __restrict__ flagNZ,
    int* __restrict__ src32, int* __restrict__ dst32, int* __restrict__ nb32) {
  bool is64 = (*flagNZ == 0);
  long i = (long)blockIdx.x * 256 + threadIdx.x;
  const int*       e32 = (const int*)edge;
  const long long* e64 = (const long long*)edge;
  const int*       n32 = (const int*)nbin;
  const long long* n64 = (const long long*)nbin;
  if (i < N_EDGES) {
    src32[i] = clampN(is64 ? (int)e64[i] : e32[i]);
    dst32[i] = clampN(is64 ? (int)e64[N_EDGES + i] : e32[N_EDGES + i]);
  }
  long j = i - N_EDGES;
  if (j >= 0 && j < N_NODES)
    nb32[j] = min(max(is64 ? (int)n64[j] : n32[j], 0), N_GRAPHS - 1);
}

// ---------------- CSR build: histogram -> hierarchical scan -> scatter ----------------
__global__ __launch_bounds__(256) void hist_kernel(
    const int* __restrict__ dst, int* __restrict__ deg) {
  int i = blockIdx.x * 256 + threadIdx.x;
  if (i >= E_TOT) return;
  int d = (i < N_EDGES) ? dst[i] : (i - N_EDGES);
  atomicAdd(&deg[d], 1);
}

#define SCAN_VPT 4
#define SCAN_BLK (256 * SCAN_VPT)
#define SCAN_NB  ((N_NODES + SCAN_BLK - 1) / SCAN_BLK)  // 49

__global__ __launch_bounds__(256) void scan_local_kernel(
    const int* __restrict__ deg, int* __restrict__ incl, int* __restrict__ blockSums) {
  __shared__ int wsum[4];
  int lane = threadIdx.x & 63, wid = threadIdx.x >> 6;
  int tbase = blockIdx.x * SCAN_BLK + threadIdx.x * SCAN_VPT;
  int v[SCAN_VPT];
  int s = 0;
#pragma unroll
  for (int j = 0; j < SCAN_VPT; ++j) {
    int i = tbase + j;
    v[j] = (i < N_NODES) ? deg[i] : 0;
    s += v[j];
  }
  int sc = s;
#pragma unroll
  for (int o = 1; o < 64; o <<= 1) {
    int t = __shfl_up(sc, o);
    if (lane >= o) sc += t;
  }
  if (lane == 63) wsum[wid] = sc;
  __syncthreads();
  int woff = 0;
  for (int w = 0; w < wid; ++w) woff += wsum[w];
  int run = woff + sc - s;
#pragma unroll
  for (int j = 0; j < SCAN_VPT; ++j) {
    run += v[j];
    int i = tbase + j;
    if (i < N_NODES) incl[i] = run;
  }
  if (threadIdx.x == 255)
    blockSums[blockIdx.x] = woff + sc;
}

__global__ __launch_bounds__(256) void scan_spine_kernel(int* __restrict__ bs) {
  __shared__ int wsum[4];
  int lane = threadIdx.x & 63, wid = threadIdx.x >> 6;
  int v = (threadIdx.x < SCAN_NB) ? bs[threadIdx.x] : 0;
  int sc = v;
#pragma unroll
  for (int o = 1; o < 64; o <<= 1) {
    int t = __shfl_up(sc, o);
    if (lane >= o) sc += t;
  }
  if (lane == 63) wsum[wid] = sc;
  __syncthreads();
  int woff = 0;
  for (int w = 0; w < wid; ++w) woff += wsum[w];
  if (threadIdx.x < SCAN_NB) bs[threadIdx.x] = woff + sc - v;  // exclusive
}

__global__ __launch_bounds__(256) void scan_add_kernel(
    const int* __restrict__ deg, const int* __restrict__ incl,
    const int* __restrict__ blockOffs,
    int* __restrict__ rowptr, int* __restrict__ pos) {
  int i = blockIdx.x * 256 + threadIdx.x;
  if (i >= N_NODES) return;
  int ic = incl[i] + blockOffs[i / SCAN_BLK];
  rowptr[i + 1] = ic;
  pos[i] = ic - deg[i];
  if (i == 0) rowptr[0] = 0;
}

__global__ __launch_bounds__(256) void scatter_kernel(
    const int* __restrict__ src, const int* __restrict__ dst,
    int* __restrict__ pos, int* __restrict__ srcS) {
  int i = blockIdx.x * 256 + threadIdx.x;
  if (i >= E_TOT) return;
  int s, d;
  if (i < N_EDGES) { s = src[i]; d = dst[i]; } else { s = d = i - N_EDGES; }
  int j = atomicAdd(&pos[d], 1);
  srcS[j] = s;
}

// ---------------- weight transpose + bf16 convert: WT[n][k] = bf16(W[k][n]) ----------------
__global__ __launch_bounds__(256) void convert_wt_kernel(
    const float* __restrict__ W, short* __restrict__ WT, int K, int N) {
  int i = blockIdx.x * 256 + threadIdx.x;
  if (i >= K * N) return;
  int n = i / K, k = i - n * K;
  WT[i] = f2bs(W[(size_t)k * N + n]);
}

// ---------------- fused relevance + bf16 convert: Abf[n][k] = bf16(x[n][k]*rel[n]) ----------------
__global__ __launch_bounds__(256) void rel_conv_kernel(
    const float* __restrict__ x, const float* __restrict__ claim,
    const int* __restrict__ nb, short* __restrict__ Abf) {
  __shared__ float buf[4];
  int n = blockIdx.x;
  int g = nb[n];
  const float* xr = x + (size_t)n * D_IN;
  const float* cr = claim + (size_t)g * D_IN;
  float xv[3];
  float dot = 0.f, nx = 0.f, nc = 0.f;
#pragma unroll
  for (int i = 0; i < 3; ++i) {
    int d = threadIdx.x + i * 256;
    xv[i] = xr[d];
    float cv = cr[d];
    dot += xv[i] * cv; nx += xv[i] * xv[i]; nc += cv * cv;
  }
  dot = blockReduce256(dot, buf);
  nx  = blockReduce256(nx, buf);
  nc  = blockReduce256(nc, buf);
  float rel = dot / fmaxf(sqrtf(nx) * sqrtf(nc), 1e-8f);
#pragma unroll
  for (int i = 0; i < 3; ++i)
    Abf[(size_t)n * D_IN + threadIdx.x + i * 256] = f2bs(xv[i] * rel);
}

// ---------------- BN scale/shift + ReLU + bf16 convert (layer-2 A) ----------------
__global__ __launch_bounds__(256) void bn_conv_kernel(
    const float* __restrict__ agg, const float* __restrict__ scale,
    const float* __restrict__ shift, short* __restrict__ A2) {
  int i = blockIdx.x * 256 + threadIdx.x;   // vec-4 index
  f32x4 v = ((const f32x4*)agg)[i];
  int col = (i << 2) & (D_HID - 1);
  short4v o;
#pragma unroll
  for (int j = 0; j < 4; ++j) {
    float t = fmaxf(v[j] * scale[col + j] + shift[col + j], 0.f);
    o[j] = f2bs(t);
  }
  ((short4v*)A2)[i] = o;
}

// ---------------- MFMA GEMM (bf16 in/out): C[M,256] = A[M,K] @ B[K,256] ----------------
// 128x128 tile per block, 4 waves (2x2), per-wave 64x64 = 4x4 MFMA tiles, BK=32.
// LDS fragment-major layout [tile][16][quad][8] so global_load_lds (linear dest,
// per-lane source) and ds_read_b128 frag reads are both conflict-free.
// Fused epilogue: alpha_s/alpha_d = acc . a (cross-lane reduce + atomicAdd), C bf16.
#define GEMM_BK 32
__global__ __launch_bounds__(256) void mfma_gemm_bf16_kernel(
    const short* __restrict__ Abf, const short* __restrict__ BT,
    const float* __restrict__ aS, const float* __restrict__ aD,
    float* __restrict__ alphaS, float* __restrict__ alphaD,
    bf16* __restrict__ C, int M, int K) {
  __shared__ short As[4096];   // 8 m-tiles * 512 shorts
  __shared__ short Bs[4096];   // 8 n-tiles * 512 shorts
  int tid = threadIdx.x;
  int wave = tid >> 6, lane = tid & 63;
  int l16 = lane & 15, quadL = lane >> 4;
  int wr = wave >> 1, wc = wave & 1;
  int mBase = (blockIdx.x >> 1) * 128;
  int nBase = (blockIdx.x & 1) * 128;

  // staging source addresses (2 rounds x {A,B}); k0 added in-loop
  const short* gA[2];
  const short* gB[2];
  int ldsOff[2];
#pragma unroll
  for (int r = 0; r < 2; ++r) {
    int slot = r * 256 + tid;              // 16B slot index 0..511
    int mt = slot >> 6, m16 = (slot >> 2) & 15, quad = slot & 3;
    int rowA = min(mBase + mt * 16 + m16, M - 1);   // clamp OOB rows (outputs masked)
    gA[r] = Abf + (size_t)rowA * K + quad * 8;
    gB[r] = BT + (size_t)(nBase + mt * 16 + m16) * K + quad * 8;
    ldsOff[r] = (r * 256 + wave * 64) * 8; // wave-uniform LDS base (shorts)
  }
  int aOff[4], bOff[4];
#pragma unroll
  for (int i = 0; i < 4; ++i) {
    aOff[i] = (wr * 4 + i) * 512 + l16 * 32 + quadL * 8;
    bOff[i] = (wc * 4 + i) * 512 + l16 * 32 + quadL * 8;
  }

  f32x4 acc[4][4] = {};

  for (int k0 = 0; k0 < K; k0 += GEMM_BK) {
#pragma unroll
    for (int r = 0; r < 2; ++r) {
      gload_lds16(gA[r] + k0, As + ldsOff[r]);
      gload_lds16(gB[r] + k0, Bs + ldsOff[r]);
    }
    __syncthreads();   // drains vmcnt before barrier
    short8 af[4], bfv[4];
#pragma unroll
    for (int i = 0; i < 4; ++i) af[i] = *(const short8*)(As + aOff[i]);
#pragma unroll
    for (int j = 0; j < 4; ++j) bfv[j] = *(const short8*)(Bs + bOff[j]);
#pragma unroll
    for (int i = 0; i < 4; ++i)
#pragma unroll
      for (int j = 0; j < 4; ++j)
        acc[i][j] = __builtin_amdgcn_mfma_f32_16x16x32_bf16(af[i], bfv[j], acc[i][j], 0, 0, 0);
    __syncthreads();
  }

  // ---- epilogue: fused alpha + bf16 store ----
  float asv[4], adv[4];
#pragma unroll
  for (int j = 0; j < 4; ++j) {
    int col = nBase + (wc * 4 + j) * 16 + l16;
    asv[j] = aS[col]; adv[j] = aD[col];
  }
#pragma unroll
  for (int i = 0; i < 4; ++i) {
    int m0 = mBase + (wr * 4 + i) * 16 + quadL * 4;
#pragma unroll
    for (int r = 0; r < 4; ++r) {
      int m = m0 + r;
      float ss = acc[i][0][r] * asv[0] + acc[i][1][r] * asv[1] +
                 acc[i][2][r] * asv[2] + acc[i][3][r] * asv[3];
      float dd = acc[i][0][r] * adv[0] + acc[i][1][r] * adv[1] +
                 acc[i][2][r] * adv[2] + acc[i][3][r] * adv[3];
#pragma unroll
      for (int o = 1; o < 16; o <<= 1) {
        ss += __shfl_xor(ss, o);
        dd += __shfl_xor(dd, o);
      }
      if (m < M) {
        if (l16 == 0) { atomicAdd(&alphaS[m], ss); atomicAdd(&alphaD[m], dd); }
#pragma unroll
        for (int j = 0; j < 4; ++j)
          C[(size_t)m * D_HID + nBase + (wc * 4 + j) * 16 + l16] =
              __float2bfloat16(acc[i][j][r]);
      }
    }
  }
}

// ---------------- fused GAT softmax + aggregate: one wave per dst node ----------------
__global__ __launch_bounds__(256) void gat_agg_kernel(
    const int* __restrict__ rowptr, const int* __restrict__ srcS,
    const float* __restrict__ as_, const float* __restrict__ ad_,
    const bf16* __restrict__ h, float* __restrict__ agg) {
  int wid = threadIdx.x >> 6, lane = threadIdx.x & 63;
  int n = blockIdx.x * 4 + wid;
  if (n >= N_NODES) return;
  int start = rowptr[n], end = rowptr[n + 1];
  float adn = ad_[n];
  float m = -1e30f;
  for (int j0 = start; j0 < end; j0 += 64) {
    int j = j0 + lane;
    if (j < end) {
      float e = as_[srcS[j]] + adn;
      e = e > 0.f ? e : 0.2f * e;
      m = fmaxf(m, e);
    }
  }
#pragma unroll
  for (int o = 32; o > 0; o >>= 1) m = fmaxf(m, __shfl_xor(m, o));
  float ssum = 0.f;
  for (int j0 = start; j0 < end; j0 += 64) {
    int j = j0 + lane;
    if (j < end) {
      float e = as_[srcS[j]] + adn;
      e = e > 0.f ? e : 0.2f * e;
      ssum += __expf(e - m);
    }
  }
#pragma unroll
  for (int o = 32; o > 0; o >>= 1) ssum += __shfl_xor(ssum, o);
  float inv = 1.f / ssum;
  float a0 = 0.f, a1 = 0.f, a2 = 0.f, a3 = 0.f;
  const unsigned short* hp = (const unsigned short*)h;
  for (int j = start; j < end; ++j) {
    int s = srcS[j];
    float e = as_[s] + adn;
    e = e > 0.f ? e : 0.2f * e;
    float attn = __expf(e - m) * inv;
    const ushort4 hv = *(const ushort4*)(hp + (size_t)s * D_HID + lane * 4);
    a0 += us2f(hv.x) * attn;
    a1 += us2f(hv.y) * attn;
    a2 += us2f(hv.z) * attn;
    a3 += us2f(hv.w) * attn;
  }
  float4 o4 = {a0, a1, a2, a3};
  *(float4*)(agg + (size_t)n * D_HID + lane * 4) = o4;
}

// ---------------- batch norm (training stats) ----------------
__global__ __launch_bounds__(256) void bn_stats_kernel(
    const float* __restrict__ h, float* __restrict__ sums, float* __restrict__ sumsq) {
  int col = threadIdx.x;
  float s = 0.f, q = 0.f;
  for (int r = blockIdx.x; r < N_NODES; r += gridDim.x) {
    float v = h[(size_t)r * D_HID + col];
    s += v; q += v * v;
  }
  atomicAdd(&sums[col], s);
  atomicAdd(&sumsq[col], q);
}

__global__ __launch_bounds__(256) void bn_finalize_kernel(
    const float* __restrict__ sums, const float* __restrict__ sumsq,
    const float* __restrict__ gamma, const float* __restrict__ beta,
    float* __restrict__ scale, float* __restrict__ shift) {
  int c = threadIdx.x;
  float mu = sums[c] / N_NODES;
  float var = fmaxf(sumsq[c] / N_NODES - mu * mu, 0.f);
  float sc = gamma[c] * rsqrtf(var + 1e-5f);
  scale[c] = sc;
  shift[c] = beta[c] - mu * sc;
}

// ---------------- mean pool (node_batch sorted) + b2 + relu ----------------
__global__ __launch_bounds__(256) void pool_kernel(
    const float* __restrict__ h, const float* __restrict__ bias2,
    const int* __restrict__ nb, float* __restrict__ pooled) {
  int col = threadIdx.x;
  float bias = bias2[col];
  int chunk = (N_NODES + gridDim.x - 1) / gridDim.x;
  int r0 = blockIdx.x * chunk;
  int r1 = min(N_NODES, r0 + chunk);
  float acc = 0.f; int cur = -1;
  for (int r = r0; r < r1; ++r) {
    int g = nb[r];
    if (g != cur) {
      if (cur >= 0) atomicAdd(&pooled[(size_t)cur * D_HID + col], acc);
      acc = 0.f; cur = g;
    }
    acc += fmaxf(h[(size_t)r * D_HID + col] + bias, 0.f);
  }
  if (cur >= 0) atomicAdd(&pooled[(size_t)cur * D_HID + col], acc);
}

__global__ __launch_bounds__(256) void count_kernel(
    const int* __restrict__ nb, float* __restrict__ counts) {
  __shared__ int cnt[N_GRAPHS];
  for (int i = threadIdx.x; i < N_GRAPHS; i += 256) cnt[i] = 0;
  __syncthreads();
  int n = blockIdx.x * 256 + threadIdx.x;
  if (n < N_NODES) atomicAdd(&cnt[nb[n]], 1);
  __syncthreads();
  for (int i = threadIdx.x; i < N_GRAPHS; i += 256)
    if (cnt[i]) atomicAdd(&counts[i], (float)cnt[i]);
}

// ---------------- classifier (OUTPUT FP32) ----------------
__global__ __launch_bounds__(256) void clf_kernel(
    const float* __restrict__ pooled, const float* __restrict__ counts,
    const float* __restrict__ claim, const float* __restrict__ clfW,
    const float* __restrict__ clfb, float* __restrict__ out) {
  __shared__ float buf[4];
  int g = blockIdx.x;
  float inv = 1.f / fmaxf(counts[g], 1.f);
  float p = 0.f;
  for (int d = threadIdx.x; d < (D_HID + D_IN); d += 256) {
    float w = clfW[d];
    float v = (d < D_HID) ? pooled[(size_t)g * D_HID + d] * inv
                          : claim[(size_t)g * D_IN + (d - D_HID)];
    p += v * w;
  }
  p = blockReduce256(p, buf);
  if (threadIdx.x == 0) out[g] = p + clfb[0];
}

extern "C" void kernel_launch(void* const* d_in, const int* in_sizes, int n_in,
                              void* d_out, int out_size, void* d_ws, size_t ws_size,
                              hipStream_t stream) {
  const float* claim = (const float*)d_in[0];
  const float* x     = (const float*)d_in[1];
  const void*  edge  = d_in[2];
  const void*  nbin  = d_in[3];
  const float* W1    = (const float*)d_in[4];
  const float* as1   = (const float*)d_in[5];
  const float* ad1   = (const float*)d_in[6];
  // d_in[7] = b1: cancels in BatchNorm
  const float* W2    = (const float*)d_in[8];
  const float* as2   = (const float*)d_in[9];
  const float* ad2   = (const float*)d_in[10];
  const float* b2v   = (const float*)d_in[11];
  const float* gamma = (const float*)d_in[12];
  const float* beta  = (const float*)d_in[13];
  const float* clfW  = (const float*)d_in[14];
  const float* clfb  = (const float*)d_in[15];
  float* out = (float*)d_out;

  char* wsb = (char*)d_ws;
  size_t off = 0;
  auto alloc = [&](size_t bytes) -> char* {
    char* p = wsb + off;
    off = (off + bytes + 255) & ~(size_t)255;
    return p;
  };
  int*   flagNZ = (int*)alloc(sizeof(int));
  int*   src32  = (int*)alloc((size_t)N_EDGES * sizeof(int));
  int*   dst32  = (int*)alloc((size_t)N_EDGES * sizeof(int));
  int*   nb32   = (int*)alloc((size_t)N_NODES * sizeof(int));
  int*   deg    = (int*)alloc((size_t)N_NODES * sizeof(int));
  int*   rowptr = (int*)alloc((size_t)(N_NODES + 1) * sizeof(int));
  int*   pos    = (int*)alloc((size_t)N_NODES * sizeof(int));
  int*   incl   = (int*)alloc((size_t)N_NODES * sizeof(int));
  int*   bsums  = (int*)alloc((size_t)SCAN_NB * sizeof(int));
  int*   srcS   = (int*)alloc((size_t)E_TOT * sizeof(int));
  short* W1T    = (short*)alloc((size_t)D_IN * D_HID * sizeof(short));
  short* W2T    = (short*)alloc((size_t)D_HID * D_HID * sizeof(short));
  float* alphas = (float*)alloc((size_t)N_NODES * sizeof(float));
  float* alphad = (float*)alloc((size_t)N_NODES * sizeof(float));
  float* bnsums = (float*)alloc(D_HID * sizeof(float));
  float* bnsq   = (float*)alloc(D_HID * sizeof(float));
  float* bnscale= (float*)alloc(D_HID * sizeof(float));
  float* bnshift= (float*)alloc(D_HID * sizeof(float));
  float* pooled = (float*)alloc((size_t)N_GRAPHS * D_HID * sizeof(float));
  float* counts = (float*)alloc((size_t)N_GRAPHS * sizeof(float));
  float* agg    = (float*)alloc((size_t)N_NODES * D_HID * sizeof(float));
  bf16*  h      = (bf16*) alloc((size_t)N_NODES * D_HID * sizeof(bf16));
  short* Abf    = (short*)alloc((size_t)N_NODES * D_IN * sizeof(short));
  short* A2     = Abf;   // layer-2 bf16 A reuses Abf (25.6 MB <= 76.8 MB)

  // ---- index normalization + CSR build ----
  hipMemsetAsync(flagNZ, 0, sizeof(int), stream);
  detect_idx_kernel<<<1, 256, 0, stream>>>((const int*)edge, flagNZ);
  normalize_idx_kernel<<<(N_EDGES + N_NODES + 255) / 256, 256, 0, stream>>>(
      edge, nbin, flagNZ, src32, dst32, nb32);
  hipMemsetAsync(deg, 0, (size_t)N_NODES * sizeof(int), stream);
  int egrid = (E_TOT + 255) / 256;
  hist_kernel<<<egrid, 256, 0, stream>>>(dst32, deg);
  scan_local_kernel<<<SCAN_NB, 256, 0, stream>>>(deg, incl, bsums);
  scan_spine_kernel<<<1, 256, 0, stream>>>(bsums);
  scan_add_kernel<<<(N_NODES + 255) / 256, 256, 0, stream>>>(deg, incl, bsums, rowptr, pos);
  scatter_kernel<<<egrid, 256, 0, stream>>>(src32, dst32, pos, srcS);

  // ---- weights -> transposed bf16 (once) ----
  convert_wt_kernel<<<(D_IN * D_HID + 255) / 256, 256, 0, stream>>>(W1, W1T, D_IN, D_HID);
  convert_wt_kernel<<<(D_HID * D_HID + 255) / 256, 256, 0, stream>>>(W2, W2T, D_HID, D_HID);

  hipMemsetAsync(bnsums, 0, D_HID * 4, stream);
  hipMemsetAsync(bnsq, 0, D_HID * 4, stream);
  hipMemsetAsync(pooled, 0, (size_t)N_GRAPHS * D_HID * 4, stream);
  hipMemsetAsync(counts, 0, (size_t)N_GRAPHS * 4, stream);

  int gemmGrid = ((N_NODES + 127) / 128) * 2;   // 391 m-tiles x 2 n-tiles

  // ---- layer 1 ----
  rel_conv_kernel<<<N_NODES, 256, 0, stream>>>(x, claim, nb32, Abf);
  hipMemsetAsync(alphas, 0, (size_t)N_NODES * 4, stream);
  hipMemsetAsync(alphad, 0, (size_t)N_NODES * 4, stream);
  mfma_gemm_bf16_kernel<<<gemmGrid, 256, 0, stream>>>(
      Abf, W1T, as1, ad1, alphas, alphad, h, N_NODES, D_IN);
  gat_agg_kernel<<<N_NODES / 4, 256, 0, stream>>>(rowptr, srcS, alphas, alphad, h, agg);

  bn_stats_kernel<<<256, 256, 0, stream>>>(agg, bnsums, bnsq);
  bn_finalize_kernel<<<1, 256, 0, stream>>>(bnsums, bnsq, gamma, beta, bnscale, bnshift);

  // ---- layer 2 (BN+ReLU folded into bf16 conversion) ----
  bn_conv_kernel<<<(N_NODES * D_HID / 4 + 255) / 256, 256, 0, stream>>>(
      agg, bnscale, bnshift, A2);
  hipMemsetAsync(alphas, 0, (size_t)N_NODES * 4, stream);
  hipMemsetAsync(alphad, 0, (size_t)N_NODES * 4, stream);
  mfma_gemm_bf16_kernel<<<gemmGrid, 256, 0, stream>>>(
      A2, W2T, as2, ad2, alphas, alphad, h, N_NODES, D_HID);
  gat_agg_kernel<<<N_NODES / 4, 256, 0, stream>>>(rowptr, srcS, alphas, alphad, h, agg);

  // ---- pool + classifier ----
  pool_kernel<<<256, 256, 0, stream>>>(agg, b2v, nb32, pooled);
  count_kernel<<<(N_NODES + 255) / 256, 256, 0, stream>>>(nb32, counts);
  clf_kernel<<<N_GRAPHS, 256, 0, stream>>>(pooled, counts, claim, clfW, clfb, out);
}

// Round 3
// 627.038 us; speedup vs baseline: 1.4915x; 1.1012x over previous
//
#include <hip/hip_runtime.h>
#include <hip/hip_bf16.h>

#define N_NODES  50000
#define N_EDGES  400000
#define E_TOT    450000   // edges + self loops
#define N_GRAPHS 128
#define D_IN     768
#define D_HID    256

typedef __hip_bfloat16 bf16;
typedef __attribute__((ext_vector_type(8))) short short8;
typedef __attribute__((ext_vector_type(4))) short short4v;
typedef __attribute__((ext_vector_type(4))) float f32x4;

__device__ __forceinline__ float b2f(bf16 v) { return __bfloat162float(v); }
__device__ __forceinline__ float us2f(unsigned short u) { return __uint_as_float((unsigned)u << 16); }
__device__ __forceinline__ int clampN(int v) { return min(max(v, 0), N_NODES - 1); }
// fp32 -> bf16 bits (RNE), as short for MFMA fragments
__device__ __forceinline__ short f2bs(float f) {
  unsigned u = __float_as_uint(f);
  return (short)((u + 0x7FFFu + ((u >> 16) & 1u)) >> 16);
}

// async global->LDS, 16B per lane. LDS dest is wave-uniform base + lane*16.
__device__ __forceinline__ void gload_lds16(const void* g, void* l) {
  __builtin_amdgcn_global_load_lds(
      (const __attribute__((address_space(1))) void*)g,
      (__attribute__((address_space(3))) void*)l, 16, 0, 0);
}

__device__ __forceinline__ float waveReduceSum(float v) {
#pragma unroll
  for (int o = 32; o > 0; o >>= 1) v += __shfl_down(v, o);
  return v;
}

__device__ __forceinline__ float blockReduce256(float v, volatile float* buf4) {
  int lane = threadIdx.x & 63, wid = threadIdx.x >> 6;
  v = waveReduceSum(v);
  if (lane == 0) buf4[wid] = v;
  __syncthreads();
  float s = buf4[0] + buf4[1] + buf4[2] + buf4[3];
  __syncthreads();
  return s;
}

// ---------------- index dtype detection (zeroes its own flag; single block) ----------------
__global__ __launch_bounds__(256) void detect_idx_kernel(
    const int* __restrict__ edge32, int* __restrict__ flagNZ) {
  if (threadIdx.x == 0) *flagNZ = 0;
  __syncthreads();
  int t = threadIdx.x;
  int nz = 0;
#pragma unroll
  for (int i = 0; i < 4; ++i) {
    int idx = 2 * (t + i * 256) + 1;
    if (edge32[idx] != 0) nz = 1;
  }
  if (nz) atomicOr(flagNZ, 1);
}

// normalize indices; also zeroes deg[] for the histogram
__global__ __launch_bounds__(256) void normalize_idx_kernel(
    const void* __restrict__ edge, const void* __restrict__ nbin,
    const int* __restrict__ flagNZ,
    int* __restrict__ src32, int* __restrict__ dst32, int* __restrict__ nb32,
    int* __restrict__ deg) {
  bool is64 = (*flagNZ == 0);
  long i = (long)blockIdx.x * 256 + threadIdx.x;
  const int*       e32 = (const int*)edge;
  const long long* e64 = (const long long*)edge;
  const int*       n32 = (const int*)nbin;
  const long long* n64 = (const long long*)nbin;
  if (i < N_NODES) deg[i] = 0;
  if (i < N_EDGES) {
    src32[i] = clampN(is64 ? (int)e64[i] : e32[i]);
    dst32[i] = clampN(is64 ? (int)e64[N_EDGES + i] : e32[N_EDGES + i]);
  }
  long j = i - N_EDGES;
  if (j >= 0 && j < N_NODES)
    nb32[j] = min(max(is64 ? (int)n64[j] : n32[j], 0), N_GRAPHS - 1);
}

// ---------------- CSR build: histogram -> hierarchical scan -> scatter ----------------
__global__ __launch_bounds__(256) void hist_kernel(
    const int* __restrict__ dst, int* __restrict__ deg) {
  int i = blockIdx.x * 256 + threadIdx.x;
  if (i >= E_TOT) return;
  int d = (i < N_EDGES) ? dst[i] : (i - N_EDGES);
  atomicAdd(&deg[d], 1);
}

#define SCAN_VPT 4
#define SCAN_BLK (256 * SCAN_VPT)
#define SCAN_NB  ((N_NODES + SCAN_BLK - 1) / SCAN_BLK)  // 49

__global__ __launch_bounds__(256) void scan_local_kernel(
    const int* __restrict__ deg, int* __restrict__ incl, int* __restrict__ blockSums) {
  __shared__ int wsum[4];
  int lane = threadIdx.x & 63, wid = threadIdx.x >> 6;
  int tbase = blockIdx.x * SCAN_BLK + threadIdx.x * SCAN_VPT;
  int v[SCAN_VPT];
  int s = 0;
#pragma unroll
  for (int j = 0; j < SCAN_VPT; ++j) {
    int i = tbase + j;
    v[j] = (i < N_NODES) ? deg[i] : 0;
    s += v[j];
  }
  int sc = s;
#pragma unroll
  for (int o = 1; o < 64; o <<= 1) {
    int t = __shfl_up(sc, o);
    if (lane >= o) sc += t;
  }
  if (lane == 63) wsum[wid] = sc;
  __syncthreads();
  int woff = 0;
  for (int w = 0; w < wid; ++w) woff += wsum[w];
  int run = woff + sc - s;
#pragma unroll
  for (int j = 0; j < SCAN_VPT; ++j) {
    run += v[j];
    int i = tbase + j;
    if (i < N_NODES) incl[i] = run;
  }
  if (threadIdx.x == 255)
    blockSums[blockIdx.x] = woff + sc;
}

// scan_add with spine folded in: each block computes its scan-block offset by
// wave-reducing the 49 raw block sums (SCAN_NB <= 64).
__global__ __launch_bounds__(256) void scan_add_kernel(
    const int* __restrict__ deg, const int* __restrict__ incl,
    const int* __restrict__ bsums,
    int* __restrict__ rowptr, int* __restrict__ pos) {
  __shared__ int offSh;
  int sb = blockIdx.x >> 2;   // 256-node block -> 1024-node scan block
  if (threadIdx.x < 64) {
    int v = (threadIdx.x < sb) ? bsums[threadIdx.x] : 0;
#pragma unroll
    for (int o = 32; o > 0; o >>= 1) v += __shfl_down(v, o);
    if (threadIdx.x == 0) offSh = v;
  }
  __syncthreads();
  int i = blockIdx.x * 256 + threadIdx.x;
  if (i >= N_NODES) return;
  int ic = incl[i] + offSh;
  rowptr[i + 1] = ic;
  pos[i] = ic - deg[i];
  if (i == 0) rowptr[0] = 0;
}

__global__ __launch_bounds__(256) void scatter_kernel(
    const int* __restrict__ src, const int* __restrict__ dst,
    int* __restrict__ pos, int* __restrict__ srcS) {
  int i = blockIdx.x * 256 + threadIdx.x;
  if (i >= E_TOT) return;
  int s, d;
  if (i < N_EDGES) { s = src[i]; d = dst[i]; } else { s = d = i - N_EDGES; }
  int j = atomicAdd(&pos[d], 1);
  srcS[j] = s;
}

// ---------------- both weight transposes in one launch ----------------
__global__ __launch_bounds__(256) void convert_wt_kernel(
    const float* __restrict__ W1, const float* __restrict__ W2,
    short* __restrict__ W1T, short* __restrict__ W2T) {
  int i = blockIdx.x * 256 + threadIdx.x;
  if (i < D_IN * D_HID) {
    int n = i / D_IN, k = i - n * D_IN;
    W1T[i] = f2bs(W1[(size_t)k * D_HID + n]);
  }
  int j = i - D_IN * D_HID;
  if (j >= 0 && j < D_HID * D_HID) {
    int n = j / D_HID, k = j - n * D_HID;
    W2T[j] = f2bs(W2[(size_t)k * D_HID + n]);
  }
}

// ---------------- fused relevance + bf16 convert; zeroes alpha and BN accumulators ----------------
__global__ __launch_bounds__(256) void rel_conv_kernel(
    const float* __restrict__ x, const float* __restrict__ claim,
    const int* __restrict__ nb, short* __restrict__ Abf,
    float* __restrict__ alphas, float* __restrict__ alphad,
    float* __restrict__ bnsums, float* __restrict__ bnsq) {
  __shared__ float buf[4];
  int n = blockIdx.x;
  if (threadIdx.x == 0) { alphas[n] = 0.f; alphad[n] = 0.f; }
  if (n == 0) { bnsums[threadIdx.x] = 0.f; bnsq[threadIdx.x] = 0.f; }
  int g = nb[n];
  const float* xr = x + (size_t)n * D_IN;
  const float* cr = claim + (size_t)g * D_IN;
  float xv[3];
  float dot = 0.f, nx = 0.f, nc = 0.f;
#pragma unroll
  for (int i = 0; i < 3; ++i) {
    int d = threadIdx.x + i * 256;
    xv[i] = xr[d];
    float cv = cr[d];
    dot += xv[i] * cv; nx += xv[i] * xv[i]; nc += cv * cv;
  }
  dot = blockReduce256(dot, buf);
  nx  = blockReduce256(nx, buf);
  nc  = blockReduce256(nc, buf);
  float rel = dot / fmaxf(sqrtf(nx) * sqrtf(nc), 1e-8f);
#pragma unroll
  for (int i = 0; i < 3; ++i)
    Abf[(size_t)n * D_IN + threadIdx.x + i * 256] = f2bs(xv[i] * rel);
}

// ---------------- BN finalize+scale/shift+ReLU+bf16 (layer-2 A); zeroes alpha + pooled ----------------
__global__ __launch_bounds__(256) void bn_conv_kernel(
    const float* __restrict__ agg, const float* __restrict__ sums,
    const float* __restrict__ sumsq, const float* __restrict__ gamma,
    const float* __restrict__ beta, short* __restrict__ A2,
    float* __restrict__ alphas, float* __restrict__ alphad,
    float* __restrict__ pooled) {
  int i = blockIdx.x * 256 + threadIdx.x;   // vec-4 index
  if ((i & 63) == 0) { int n = i >> 6; alphas[n] = 0.f; alphad[n] = 0.f; }
  if (i < N_GRAPHS * D_HID) pooled[i] = 0.f;
  f32x4 v = ((const f32x4*)agg)[i];
  int col = (i << 2) & (D_HID - 1);
  short4v o;
#pragma unroll
  for (int j = 0; j < 4; ++j) {
    float mu  = sums[col + j] * (1.f / N_NODES);
    float var = fmaxf(sumsq[col + j] * (1.f / N_NODES) - mu * mu, 0.f);
    float sc  = gamma[col + j] * rsqrtf(var + 1e-5f);
    float sh  = beta[col + j] - mu * sc;
    float t = fmaxf(v[j] * sc + sh, 0.f);
    o[j] = f2bs(t);
  }
  ((short4v*)A2)[i] = o;
}

// ---------------- MFMA GEMM (bf16 in/out): C[M,256] = A[M,K] @ B[K,256] ----------------
// 128x128 tile per block, 4 waves (2x2), per-wave 64x64 = 4x4 MFMA tiles, BK=32.
// LDS fragment-major layout so global_load_lds (linear dest, per-lane source)
// and ds_read_b128 frag reads are both conflict-free.
// Fused epilogue: alpha_s/alpha_d = acc . a (cross-lane reduce + atomicAdd), C bf16.
#define GEMM_BK 32
__global__ __launch_bounds__(256) void mfma_gemm_bf16_kernel(
    const short* __restrict__ Abf, const short* __restrict__ BT,
    const float* __restrict__ aS, const float* __restrict__ aD,
    float* __restrict__ alphaS, float* __restrict__ alphaD,
    bf16* __restrict__ C, int M, int K) {
  __shared__ short As[4096];   // 8 m-tiles * 512 shorts
  __shared__ short Bs[4096];   // 8 n-tiles * 512 shorts
  int tid = threadIdx.x;
  int wave = tid >> 6, lane = tid & 63;
  int l16 = lane & 15, quadL = lane >> 4;
  int wr = wave >> 1, wc = wave & 1;
  int mBase = (blockIdx.x >> 1) * 128;
  int nBase = (blockIdx.x & 1) * 128;

  const short* gA[2];
  const short* gB[2];
  int ldsOff[2];
#pragma unroll
  for (int r = 0; r < 2; ++r) {
    int slot = r * 256 + tid;              // 16B slot index 0..511
    int mt = slot >> 6, m16 = (slot >> 2) & 15, quad = slot & 3;
    int rowA = min(mBase + mt * 16 + m16, M - 1);   // clamp OOB rows (outputs masked)
    gA[r] = Abf + (size_t)rowA * K + quad * 8;
    gB[r] = BT + (size_t)(nBase + mt * 16 + m16) * K + quad * 8;
    ldsOff[r] = (r * 256 + wave * 64) * 8; // wave-uniform LDS base (shorts)
  }
  int aOff[4], bOff[4];
#pragma unroll
  for (int i = 0; i < 4; ++i) {
    aOff[i] = (wr * 4 + i) * 512 + l16 * 32 + quadL * 8;
    bOff[i] = (wc * 4 + i) * 512 + l16 * 32 + quadL * 8;
  }

  f32x4 acc[4][4] = {};

  for (int k0 = 0; k0 < K; k0 += GEMM_BK) {
#pragma unroll
    for (int r = 0; r < 2; ++r) {
      gload_lds16(gA[r] + k0, As + ldsOff[r]);
      gload_lds16(gB[r] + k0, Bs + ldsOff[r]);
    }
    __syncthreads();   // drains vmcnt before barrier
    short8 af[4], bfv[4];
#pragma unroll
    for (int i = 0; i < 4; ++i) af[i] = *(const short8*)(As + aOff[i]);
#pragma unroll
    for (int j = 0; j < 4; ++j) bfv[j] = *(const short8*)(Bs + bOff[j]);
#pragma unroll
    for (int i = 0; i < 4; ++i)
#pragma unroll
      for (int j = 0; j < 4; ++j)
        acc[i][j] = __builtin_amdgcn_mfma_f32_16x16x32_bf16(af[i], bfv[j], acc[i][j], 0, 0, 0);
    __syncthreads();
  }

  // ---- epilogue: fused alpha + bf16 store ----
  float asv[4], adv[4];
#pragma unroll
  for (int j = 0; j < 4; ++j) {
    int col = nBase + (wc * 4 + j) * 16 + l16;
    asv[j] = aS[col]; adv[j] = aD[col];
  }
#pragma unroll
  for (int i = 0; i < 4; ++i) {
    int m0 = mBase + (wr * 4 + i) * 16 + quadL * 4;
#pragma unroll
    for (int r = 0; r < 4; ++r) {
      int m = m0 + r;
      float ss = acc[i][0][r] * asv[0] + acc[i][1][r] * asv[1] +
                 acc[i][2][r] * asv[2] + acc[i][3][r] * asv[3];
      float dd = acc[i][0][r] * adv[0] + acc[i][1][r] * adv[1] +
                 acc[i][2][r] * adv[2] + acc[i][3][r] * adv[3];
#pragma unroll
      for (int o = 1; o < 16; o <<= 1) {
        ss += __shfl_xor(ss, o);
        dd += __shfl_xor(dd, o);
      }
      if (m < M) {
        if (l16 == 0) { atomicAdd(&alphaS[m], ss); atomicAdd(&alphaD[m], dd); }
#pragma unroll
        for (int j = 0; j < 4; ++j)
          C[(size_t)m * D_HID + nBase + (wc * 4 + j) * 16 + l16] =
              __float2bfloat16(acc[i][j][r]);
      }
    }
  }
}

// ---------------- fused GAT softmax + aggregate: one wave per dst node ----------------
// Single gather pass: chunk-0 edges (deg<=64 ~ all nodes) cached in registers,
// redistributed via shfl in the aggregate loop; 1/ssum factored out.
__global__ __launch_bounds__(256) void gat_agg_kernel(
    const int* __restrict__ rowptr, const int* __restrict__ srcS,
    const float* __restrict__ as_, const float* __restrict__ ad_,
    const bf16* __restrict__ h, float* __restrict__ agg) {
  int wid = threadIdx.x >> 6, lane = threadIdx.x & 63;
  int n = blockIdx.x * 4 + wid;
  if (n >= N_NODES) return;
  int start = rowptr[n], end = rowptr[n + 1];
  int deg = end - start;
  float adn = ad_[n];
  // cache chunk 0 in registers
  int sidx = 0;
  float e0 = -1e30f;
  if (lane < deg) {
    sidx = srcS[start + lane];
    float e = as_[sidx] + adn;
    e0 = e > 0.f ? e : 0.2f * e;
  }
  float m = e0;
  for (int j0 = start + 64; j0 < end; j0 += 64) {   // rare (deg > 64)
    int j = j0 + lane;
    if (j < end) {
      float e = as_[srcS[j]] + adn;
      e = e > 0.f ? e : 0.2f * e;
      m = fmaxf(m, e);
    }
  }
#pragma unroll
  for (int o = 32; o > 0; o >>= 1) m = fmaxf(m, __shfl_xor(m, o));
  float ssum = (lane < deg) ? __expf(e0 - m) : 0.f;
  for (int j0 = start + 64; j0 < end; j0 += 64) {
    int j = j0 + lane;
    if (j < end) {
      float e = as_[srcS[j]] + adn;
      e = e > 0.f ? e : 0.2f * e;
      ssum += __expf(e - m);
    }
  }
#pragma unroll
  for (int o = 32; o > 0; o >>= 1) ssum += __shfl_xor(ssum, o);
  float a0 = 0.f, a1 = 0.f, a2 = 0.f, a3 = 0.f;
  const unsigned short* hp = (const unsigned short*)h;
  int c0 = min(deg, 64);
  for (int t = 0; t < c0; ++t) {
    int s = __shfl(sidx, t);
    float ev = __shfl(e0, t);
    float w = __expf(ev - m);
    const ushort4 hv = *(const ushort4*)(hp + (size_t)s * D_HID + lane * 4);
    a0 += us2f(hv.x) * w;
    a1 += us2f(hv.y) * w;
    a2 += us2f(hv.z) * w;
    a3 += us2f(hv.w) * w;
  }
  for (int j = start + 64; j < end; ++j) {   // rare tail
    int s = srcS[j];
    float e = as_[s] + adn;
    e = e > 0.f ? e : 0.2f * e;
    float w = __expf(e - m);
    const ushort4 hv = *(const ushort4*)(hp + (size_t)s * D_HID + lane * 4);
    a0 += us2f(hv.x) * w;
    a1 += us2f(hv.y) * w;
    a2 += us2f(hv.z) * w;
    a3 += us2f(hv.w) * w;
  }
  float inv = 1.f / ssum;
  float4 o4 = {a0 * inv, a1 * inv, a2 * inv, a3 * inv};
  *(float4*)(agg + (size_t)n * D_HID + lane * 4) = o4;
}

// ---------------- batch norm stats (accumulators pre-zeroed by rel_conv) ----------------
__global__ __launch_bounds__(256) void bn_stats_kernel(
    const float* __restrict__ h, float* __restrict__ sums, float* __restrict__ sumsq) {
  int col = threadIdx.x;
  float s = 0.f, q = 0.f;
  for (int r = blockIdx.x; r < N_NODES; r += gridDim.x) {
    float v = h[(size_t)r * D_HID + col];
    s += v; q += v * v;
  }
  atomicAdd(&sums[col], s);
  atomicAdd(&sumsq[col], q);
}

// ---------------- mean pool (node_batch sorted) + b2 + relu ----------------
__global__ __launch_bounds__(256) void pool_kernel(
    const float* __restrict__ h, const float* __restrict__ bias2,
    const int* __restrict__ nb, float* __restrict__ pooled) {
  int col = threadIdx.x;
  float bias = bias2[col];
  int chunk = (N_NODES + gridDim.x - 1) / gridDim.x;
  int r0 = blockIdx.x * chunk;
  int r1 = min(N_NODES, r0 + chunk);
  float acc = 0.f; int cur = -1;
  for (int r = r0; r < r1; ++r) {
    int g = nb[r];
    if (g != cur) {
      if (cur >= 0) atomicAdd(&pooled[(size_t)cur * D_HID + col], acc);
      acc = 0.f; cur = g;
    }
    acc += fmaxf(h[(size_t)r * D_HID + col] + bias, 0.f);
  }
  if (cur >= 0) atomicAdd(&pooled[(size_t)cur * D_HID + col], acc);
}

// ---------------- classifier; per-graph count via binary search on sorted nb ----------------
__global__ __launch_bounds__(256) void clf_kernel(
    const float* __restrict__ pooled, const int* __restrict__ nb,
    const float* __restrict__ claim, const float* __restrict__ clfW,
    const float* __restrict__ clfb, float* __restrict__ out) {
  __shared__ float buf[4];
  __shared__ int cntSh;
  int g = blockIdx.x;
  if (threadIdx.x == 0) {
    int lo = 0, hi = N_NODES;
    while (lo < hi) { int mid = (lo + hi) >> 1; if (nb[mid] < g) lo = mid + 1; else hi = mid; }
    int lb = lo; hi = N_NODES;
    while (lo < hi) { int mid = (lo + hi) >> 1; if (nb[mid] <= g) lo = mid + 1; else hi = mid; }
    cntSh = lo - lb;
  }
  __syncthreads();
  float inv = 1.f / fmaxf((float)cntSh, 1.f);
  float p = 0.f;
  for (int d = threadIdx.x; d < (D_HID + D_IN); d += 256) {
    float w = clfW[d];
    float v = (d < D_HID) ? pooled[(size_t)g * D_HID + d] * inv
                          : claim[(size_t)g * D_IN + (d - D_HID)];
    p += v * w;
  }
  p = blockReduce256(p, buf);
  if (threadIdx.x == 0) out[g] = p + clfb[0];
}

extern "C" void kernel_launch(void* const* d_in, const int* in_sizes, int n_in,
                              void* d_out, int out_size, void* d_ws, size_t ws_size,
                              hipStream_t stream) {
  const float* claim = (const float*)d_in[0];
  const float* x     = (const float*)d_in[1];
  const void*  edge  = d_in[2];
  const void*  nbin  = d_in[3];
  const float* W1    = (const float*)d_in[4];
  const float* as1   = (const float*)d_in[5];
  const float* ad1   = (const float*)d_in[6];
  // d_in[7] = b1: cancels in BatchNorm
  const float* W2    = (const float*)d_in[8];
  const float* as2   = (const float*)d_in[9];
  const float* ad2   = (const float*)d_in[10];
  const float* b2v   = (const float*)d_in[11];
  const float* gamma = (const float*)d_in[12];
  const float* beta  = (const float*)d_in[13];
  const float* clfW  = (const float*)d_in[14];
  const float* clfb  = (const float*)d_in[15];
  float* out = (float*)d_out;

  char* wsb = (char*)d_ws;
  size_t off = 0;
  auto alloc = [&](size_t bytes) -> char* {
    char* p = wsb + off;
    off = (off + bytes + 255) & ~(size_t)255;
    return p;
  };
  int*   flagNZ = (int*)alloc(sizeof(int));
  int*   src32  = (int*)alloc((size_t)N_EDGES * sizeof(int));
  int*   dst32  = (int*)alloc((size_t)N_EDGES * sizeof(int));
  int*   nb32   = (int*)alloc((size_t)N_NODES * sizeof(int));
  int*   deg    = (int*)alloc((size_t)N_NODES * sizeof(int));
  int*   rowptr = (int*)alloc((size_t)(N_NODES + 1) * sizeof(int));
  int*   pos    = (int*)alloc((size_t)N_NODES * sizeof(int));
  int*   incl   = (int*)alloc((size_t)N_NODES * sizeof(int));
  int*   bsums  = (int*)alloc((size_t)SCAN_NB * sizeof(int));
  int*   srcS   = (int*)alloc((size_t)E_TOT * sizeof(int));
  short* W1T    = (short*)alloc((size_t)D_IN * D_HID * sizeof(short));
  short* W2T    = (short*)alloc((size_t)D_HID * D_HID * sizeof(short));
  float* alphas = (float*)alloc((size_t)N_NODES * sizeof(float));
  float* alphad = (float*)alloc((size_t)N_NODES * sizeof(float));
  float* bnsums = (float*)alloc(D_HID * sizeof(float));
  float* bnsq   = (float*)alloc(D_HID * sizeof(float));
  float* pooled = (float*)alloc((size_t)N_GRAPHS * D_HID * sizeof(float));
  float* agg    = (float*)alloc((size_t)N_NODES * D_HID * sizeof(float));
  bf16*  h      = (bf16*) alloc((size_t)N_NODES * D_HID * sizeof(bf16));
  short* Abf    = (short*)alloc((size_t)N_NODES * D_IN * sizeof(short));
  short* A2     = Abf;   // layer-2 bf16 A reuses Abf

  // ---- index normalization + CSR build (no memsets: kernels self-initialize) ----
  detect_idx_kernel<<<1, 256, 0, stream>>>((const int*)edge, flagNZ);
  normalize_idx_kernel<<<(N_EDGES + N_NODES + 255) / 256, 256, 0, stream>>>(
      edge, nbin, flagNZ, src32, dst32, nb32, deg);
  int egrid = (E_TOT + 255) / 256;
  hist_kernel<<<egrid, 256, 0, stream>>>(dst32, deg);
  scan_local_kernel<<<SCAN_NB, 256, 0, stream>>>(deg, incl, bsums);
  scan_add_kernel<<<(N_NODES + 255) / 256, 256, 0, stream>>>(deg, incl, bsums, rowptr, pos);
  scatter_kernel<<<egrid, 256, 0, stream>>>(src32, dst32, pos, srcS);

  // ---- weights -> transposed bf16 (one launch) ----
  convert_wt_kernel<<<(D_IN * D_HID + D_HID * D_HID + 255) / 256, 256, 0, stream>>>(
      W1, W2, W1T, W2T);

  int gemmGrid = ((N_NODES + 127) / 128) * 2;   // 391 m-tiles x 2 n-tiles

  // ---- layer 1 ----
  rel_conv_kernel<<<N_NODES, 256, 0, stream>>>(
      x, claim, nb32, Abf, alphas, alphad, bnsums, bnsq);
  mfma_gemm_bf16_kernel<<<gemmGrid, 256, 0, stream>>>(
      Abf, W1T, as1, ad1, alphas, alphad, h, N_NODES, D_IN);
  gat_agg_kernel<<<N_NODES / 4, 256, 0, stream>>>(rowptr, srcS, alphas, alphad, h, agg);

  bn_stats_kernel<<<256, 256, 0, stream>>>(agg, bnsums, bnsq);

  // ---- layer 2 (BN finalize + scale/shift + ReLU folded into bf16 conversion) ----
  bn_conv_kernel<<<(N_NODES * D_HID / 4 + 255) / 256, 256, 0, stream>>>(
      agg, bnsums, bnsq, gamma, beta, A2, alphas, alphad, pooled);
  mfma_gemm_bf16_kernel<<<gemmGrid, 256, 0, stream>>>(
      A2, W2T, as2, ad2, alphas, alphad, h, N_NODES, D_HID);
  gat_agg_kernel<<<N_NODES / 4, 256, 0, stream>>>(rowptr, srcS, alphas, alphad, h, agg);

  // ---- pool + classifier ----
  pool_kernel<<<256, 256, 0, stream>>>(agg, b2v, nb32, pooled);
  clf_kernel<<<N_GRAPHS, 256, 0, stream>>>(pooled, nb32, claim, clfW, clfb, out);
}

// Round 4
// 612.859 us; speedup vs baseline: 1.5260x; 1.0231x over previous
//
#include <hip/hip_runtime.h>
#include <hip/hip_bf16.h>

#define N_NODES  50000
#define N_EDGES  400000
#define E_TOT    450000   // edges + self loops
#define N_GRAPHS 128
#define D_IN     768
#define D_HID    256

typedef __hip_bfloat16 bf16;
typedef __attribute__((ext_vector_type(8))) short short8;
typedef __attribute__((ext_vector_type(4))) short short4v;
typedef __attribute__((ext_vector_type(4))) float f32x4;

__device__ __forceinline__ float b2f(bf16 v) { return __bfloat162float(v); }
__device__ __forceinline__ float us2f(unsigned short u) { return __uint_as_float((unsigned)u << 16); }
__device__ __forceinline__ int clampN(int v) { return min(max(v, 0), N_NODES - 1); }
// fp32 -> bf16 bits (RNE), as short for MFMA fragments
__device__ __forceinline__ short f2bs(float f) {
  unsigned u = __float_as_uint(f);
  return (short)((u + 0x7FFFu + ((u >> 16) & 1u)) >> 16);
}

// async global->LDS, 16B per lane. LDS dest is wave-uniform base + lane*16.
__device__ __forceinline__ void gload_lds16(const void* g, void* l) {
  __builtin_amdgcn_global_load_lds(
      (const __attribute__((address_space(1))) void*)g,
      (__attribute__((address_space(3))) void*)l, 16, 0, 0);
}

__device__ __forceinline__ float waveReduceSum(float v) {
#pragma unroll
  for (int o = 32; o > 0; o >>= 1) v += __shfl_down(v, o);
  return v;
}

__device__ __forceinline__ float blockReduce256(float v, volatile float* buf4) {
  int lane = threadIdx.x & 63, wid = threadIdx.x >> 6;
  v = waveReduceSum(v);
  if (lane == 0) buf4[wid] = v;
  __syncthreads();
  float s = buf4[0] + buf4[1] + buf4[2] + buf4[3];
  __syncthreads();
  return s;
}

// ---------------- index dtype detection (zeroes its own flag; single block) ----------------
__global__ __launch_bounds__(256) void detect_idx_kernel(
    const int* __restrict__ edge32, int* __restrict__ flagNZ) {
  if (threadIdx.x == 0) *flagNZ = 0;
  __syncthreads();
  int t = threadIdx.x;
  int nz = 0;
#pragma unroll
  for (int i = 0; i < 4; ++i) {
    int idx = 2 * (t + i * 256) + 1;
    if (edge32[idx] != 0) nz = 1;
  }
  if (nz) atomicOr(flagNZ, 1);
}

// normalize indices; also zeroes deg[] for the histogram
__global__ __launch_bounds__(256) void normalize_idx_kernel(
    const void* __restrict__ edge, const void* __restrict__ nbin,
    const int* __restrict__ flagNZ,
    int* __restrict__ src32, int* __restrict__ dst32, int* __restrict__ nb32,
    int* __restrict__ deg) {
  bool is64 = (*flagNZ == 0);
  long i = (long)blockIdx.x * 256 + threadIdx.x;
  const int*       e32 = (const int*)edge;
  const long long* e64 = (const long long*)edge;
  const int*       n32 = (const int*)nbin;
  const long long* n64 = (const long long*)nbin;
  if (i < N_NODES) deg[i] = 0;
  if (i < N_EDGES) {
    src32[i] = clampN(is64 ? (int)e64[i] : e32[i]);
    dst32[i] = clampN(is64 ? (int)e64[N_EDGES + i] : e32[N_EDGES + i]);
  }
  long j = i - N_EDGES;
  if (j >= 0 && j < N_NODES)
    nb32[j] = min(max(is64 ? (int)n64[j] : n32[j], 0), N_GRAPHS - 1);
}

// ---------------- CSR build: histogram -> hierarchical scan -> scatter ----------------
__global__ __launch_bounds__(256) void hist_kernel(
    const int* __restrict__ dst, int* __restrict__ deg) {
  int i = blockIdx.x * 256 + threadIdx.x;
  if (i >= E_TOT) return;
  int d = (i < N_EDGES) ? dst[i] : (i - N_EDGES);
  atomicAdd(&deg[d], 1);
}

#define SCAN_VPT 4
#define SCAN_BLK (256 * SCAN_VPT)
#define SCAN_NB  ((N_NODES + SCAN_BLK - 1) / SCAN_BLK)  // 49

__global__ __launch_bounds__(256) void scan_local_kernel(
    const int* __restrict__ deg, int* __restrict__ incl, int* __restrict__ blockSums) {
  __shared__ int wsum[4];
  int lane = threadIdx.x & 63, wid = threadIdx.x >> 6;
  int tbase = blockIdx.x * SCAN_BLK + threadIdx.x * SCAN_VPT;
  int v[SCAN_VPT];
  int s = 0;
#pragma unroll
  for (int j = 0; j < SCAN_VPT; ++j) {
    int i = tbase + j;
    v[j] = (i < N_NODES) ? deg[i] : 0;
    s += v[j];
  }
  int sc = s;
#pragma unroll
  for (int o = 1; o < 64; o <<= 1) {
    int t = __shfl_up(sc, o);
    if (lane >= o) sc += t;
  }
  if (lane == 63) wsum[wid] = sc;
  __syncthreads();
  int woff = 0;
  for (int w = 0; w < wid; ++w) woff += wsum[w];
  int run = woff + sc - s;
#pragma unroll
  for (int j = 0; j < SCAN_VPT; ++j) {
    run += v[j];
    int i = tbase + j;
    if (i < N_NODES) incl[i] = run;
  }
  if (threadIdx.x == 255)
    blockSums[blockIdx.x] = woff + sc;
}

// scan_add with spine folded in: each block computes its scan-block offset by
// wave-reducing the 49 raw block sums (SCAN_NB <= 64).
__global__ __launch_bounds__(256) void scan_add_kernel(
    const int* __restrict__ deg, const int* __restrict__ incl,
    const int* __restrict__ bsums,
    int* __restrict__ rowptr, int* __restrict__ pos) {
  __shared__ int offSh;
  int sb = blockIdx.x >> 2;   // 256-node block -> 1024-node scan block
  if (threadIdx.x < 64) {
    int v = (threadIdx.x < sb) ? bsums[threadIdx.x] : 0;
#pragma unroll
    for (int o = 32; o > 0; o >>= 1) v += __shfl_down(v, o);
    if (threadIdx.x == 0) offSh = v;
  }
  __syncthreads();
  int i = blockIdx.x * 256 + threadIdx.x;
  if (i >= N_NODES) return;
  int ic = incl[i] + offSh;
  rowptr[i + 1] = ic;
  pos[i] = ic - deg[i];
  if (i == 0) rowptr[0] = 0;
}

__global__ __launch_bounds__(256) void scatter_kernel(
    const int* __restrict__ src, const int* __restrict__ dst,
    int* __restrict__ pos, int* __restrict__ srcS) {
  int i = blockIdx.x * 256 + threadIdx.x;
  if (i >= E_TOT) return;
  int s, d;
  if (i < N_EDGES) { s = src[i]; d = dst[i]; } else { s = d = i - N_EDGES; }
  int j = atomicAdd(&pos[d], 1);
  srcS[j] = s;
}

// ---------------- both weight transposes in one launch ----------------
__global__ __launch_bounds__(256) void convert_wt_kernel(
    const float* __restrict__ W1, const float* __restrict__ W2,
    short* __restrict__ W1T, short* __restrict__ W2T) {
  int i = blockIdx.x * 256 + threadIdx.x;
  if (i < D_IN * D_HID) {
    int n = i / D_IN, k = i - n * D_IN;
    W1T[i] = f2bs(W1[(size_t)k * D_HID + n]);
  }
  int j = i - D_IN * D_HID;
  if (j >= 0 && j < D_HID * D_HID) {
    int n = j / D_HID, k = j - n * D_HID;
    W2T[j] = f2bs(W2[(size_t)k * D_HID + n]);
  }
}

// ---------------- fused relevance + bf16 convert: ONE WAVE PER NODE ----------------
// Lane holds 12 elems (3x f32x4) in registers; 3 reductions are pure shfl_xor
// butterflies (no LDS, no barriers). Zeroes alpha and BN accumulators.
__global__ __launch_bounds__(256) void rel_conv_kernel(
    const float* __restrict__ x, const float* __restrict__ claim,
    const int* __restrict__ nb, short* __restrict__ Abf,
    float* __restrict__ alphas, float* __restrict__ alphad,
    float* __restrict__ bnsums, float* __restrict__ bnsq) {
  int wid = threadIdx.x >> 6, lane = threadIdx.x & 63;
  int n = blockIdx.x * 4 + wid;     // N_NODES % 4 == 0
  if (blockIdx.x == 0) { bnsums[threadIdx.x] = 0.f; bnsq[threadIdx.x] = 0.f; }
  if (n >= N_NODES) return;
  if (lane == 0) { alphas[n] = 0.f; alphad[n] = 0.f; }
  int g = nb[n];
  const f32x4* xr = (const f32x4*)(x + (size_t)n * D_IN);
  const f32x4* cr = (const f32x4*)(claim + (size_t)g * D_IN);
  f32x4 xv[3];
  float dot = 0.f, nx = 0.f, nc = 0.f;
#pragma unroll
  for (int j = 0; j < 3; ++j) {
    xv[j] = xr[lane + j * 64];
    f32x4 cv = cr[lane + j * 64];
#pragma unroll
    for (int k = 0; k < 4; ++k) {
      dot += xv[j][k] * cv[k];
      nx  += xv[j][k] * xv[j][k];
      nc  += cv[k] * cv[k];
    }
  }
#pragma unroll
  for (int o = 32; o > 0; o >>= 1) {
    dot += __shfl_xor(dot, o);
    nx  += __shfl_xor(nx, o);
    nc  += __shfl_xor(nc, o);
  }
  float rel = dot / fmaxf(sqrtf(nx) * sqrtf(nc), 1e-8f);
  short4v* ab = (short4v*)(Abf + (size_t)n * D_IN);
#pragma unroll
  for (int j = 0; j < 3; ++j) {
    short4v o4;
#pragma unroll
    for (int k = 0; k < 4; ++k) o4[k] = f2bs(xv[j][k] * rel);
    ab[lane + j * 64] = o4;
  }
}

// ---------------- BN finalize+scale/shift+ReLU+bf16 (layer-2 A); zeroes alpha + pooled ----------------
__global__ __launch_bounds__(256) void bn_conv_kernel(
    const float* __restrict__ agg, const float* __restrict__ sums,
    const float* __restrict__ sumsq, const float* __restrict__ gamma,
    const float* __restrict__ beta, short* __restrict__ A2,
    float* __restrict__ alphas, float* __restrict__ alphad,
    float* __restrict__ pooled) {
  int i = blockIdx.x * 256 + threadIdx.x;   // vec-4 index
  if ((i & 63) == 0) { int n = i >> 6; alphas[n] = 0.f; alphad[n] = 0.f; }
  if (i < N_GRAPHS * D_HID) pooled[i] = 0.f;
  f32x4 v = ((const f32x4*)agg)[i];
  int col = (i << 2) & (D_HID - 1);
  short4v o;
#pragma unroll
  for (int j = 0; j < 4; ++j) {
    float mu  = sums[col + j] * (1.f / N_NODES);
    float var = fmaxf(sumsq[col + j] * (1.f / N_NODES) - mu * mu, 0.f);
    float sc  = gamma[col + j] * rsqrtf(var + 1e-5f);
    float sh  = beta[col + j] - mu * sc;
    float t = fmaxf(v[j] * sc + sh, 0.f);
    o[j] = f2bs(t);
  }
  ((short4v*)A2)[i] = o;
}

// ---------------- MFMA GEMM (bf16 in/out): C[M,256] = A[M,K] @ B[K,256] ----------------
// 128x128 tile per block, 4 waves (2x2), per-wave 64x64 = 4x4 MFMA tiles, BK=32.
// LDS fragment-major layout so global_load_lds (linear dest, per-lane source)
// and ds_read_b128 frag reads are both conflict-free.
// Fused epilogue: alpha_s/alpha_d = acc . a (cross-lane reduce + atomicAdd), C bf16.
#define GEMM_BK 32
__global__ __launch_bounds__(256) void mfma_gemm_bf16_kernel(
    const short* __restrict__ Abf, const short* __restrict__ BT,
    const float* __restrict__ aS, const float* __restrict__ aD,
    float* __restrict__ alphaS, float* __restrict__ alphaD,
    bf16* __restrict__ C, int M, int K) {
  __shared__ short As[4096];   // 8 m-tiles * 512 shorts
  __shared__ short Bs[4096];   // 8 n-tiles * 512 shorts
  int tid = threadIdx.x;
  int wave = tid >> 6, lane = tid & 63;
  int l16 = lane & 15, quadL = lane >> 4;
  int wr = wave >> 1, wc = wave & 1;
  int mBase = (blockIdx.x >> 1) * 128;
  int nBase = (blockIdx.x & 1) * 128;

  const short* gA[2];
  const short* gB[2];
  int ldsOff[2];
#pragma unroll
  for (int r = 0; r < 2; ++r) {
    int slot = r * 256 + tid;              // 16B slot index 0..511
    int mt = slot >> 6, m16 = (slot >> 2) & 15, quad = slot & 3;
    int rowA = min(mBase + mt * 16 + m16, M - 1);   // clamp OOB rows (outputs masked)
    gA[r] = Abf + (size_t)rowA * K + quad * 8;
    gB[r] = BT + (size_t)(nBase + mt * 16 + m16) * K + quad * 8;
    ldsOff[r] = (r * 256 + wave * 64) * 8; // wave-uniform LDS base (shorts)
  }
  int aOff[4], bOff[4];
#pragma unroll
  for (int i = 0; i < 4; ++i) {
    aOff[i] = (wr * 4 + i) * 512 + l16 * 32 + quadL * 8;
    bOff[i] = (wc * 4 + i) * 512 + l16 * 32 + quadL * 8;
  }

  f32x4 acc[4][4] = {};

  for (int k0 = 0; k0 < K; k0 += GEMM_BK) {
#pragma unroll
    for (int r = 0; r < 2; ++r) {
      gload_lds16(gA[r] + k0, As + ldsOff[r]);
      gload_lds16(gB[r] + k0, Bs + ldsOff[r]);
    }
    __syncthreads();   // drains vmcnt before barrier
    short8 af[4], bfv[4];
#pragma unroll
    for (int i = 0; i < 4; ++i) af[i] = *(const short8*)(As + aOff[i]);
#pragma unroll
    for (int j = 0; j < 4; ++j) bfv[j] = *(const short8*)(Bs + bOff[j]);
#pragma unroll
    for (int i = 0; i < 4; ++i)
#pragma unroll
      for (int j = 0; j < 4; ++j)
        acc[i][j] = __builtin_amdgcn_mfma_f32_16x16x32_bf16(af[i], bfv[j], acc[i][j], 0, 0, 0);
    __syncthreads();
  }

  // ---- epilogue: fused alpha + bf16 store ----
  float asv[4], adv[4];
#pragma unroll
  for (int j = 0; j < 4; ++j) {
    int col = nBase + (wc * 4 + j) * 16 + l16;
    asv[j] = aS[col]; adv[j] = aD[col];
  }
#pragma unroll
  for (int i = 0; i < 4; ++i) {
    int m0 = mBase + (wr * 4 + i) * 16 + quadL * 4;
#pragma unroll
    for (int r = 0; r < 4; ++r) {
      int m = m0 + r;
      float ss = acc[i][0][r] * asv[0] + acc[i][1][r] * asv[1] +
                 acc[i][2][r] * asv[2] + acc[i][3][r] * asv[3];
      float dd = acc[i][0][r] * adv[0] + acc[i][1][r] * adv[1] +
                 acc[i][2][r] * adv[2] + acc[i][3][r] * adv[3];
#pragma unroll
      for (int o = 1; o < 16; o <<= 1) {
        ss += __shfl_xor(ss, o);
        dd += __shfl_xor(dd, o);
      }
      if (m < M) {
        if (l16 == 0) { atomicAdd(&alphaS[m], ss); atomicAdd(&alphaD[m], dd); }
#pragma unroll
        for (int j = 0; j < 4; ++j)
          C[(size_t)m * D_HID + nBase + (wc * 4 + j) * 16 + l16] =
              __float2bfloat16(acc[i][j][r]);
      }
    }
  }
}

// ---------------- fused GAT softmax + aggregate: one wave per dst node ----------------
// Single gather pass: chunk-0 edges (deg<=64 ~ all nodes) cached in registers,
// redistributed via shfl in the aggregate loop; 1/ssum factored out.
__global__ __launch_bounds__(256) void gat_agg_kernel(
    const int* __restrict__ rowptr, const int* __restrict__ srcS,
    const float* __restrict__ as_, const float* __restrict__ ad_,
    const bf16* __restrict__ h, float* __restrict__ agg) {
  int wid = threadIdx.x >> 6, lane = threadIdx.x & 63;
  int n = blockIdx.x * 4 + wid;
  if (n >= N_NODES) return;
  int start = rowptr[n], end = rowptr[n + 1];
  int deg = end - start;
  float adn = ad_[n];
  // cache chunk 0 in registers
  int sidx = 0;
  float e0 = -1e30f;
  if (lane < deg) {
    sidx = srcS[start + lane];
    float e = as_[sidx] + adn;
    e0 = e > 0.f ? e : 0.2f * e;
  }
  float m = e0;
  for (int j0 = start + 64; j0 < end; j0 += 64) {   // rare (deg > 64)
    int j = j0 + lane;
    if (j < end) {
      float e = as_[srcS[j]] + adn;
      e = e > 0.f ? e : 0.2f * e;
      m = fmaxf(m, e);
    }
  }
#pragma unroll
  for (int o = 32; o > 0; o >>= 1) m = fmaxf(m, __shfl_xor(m, o));
  float ssum = (lane < deg) ? __expf(e0 - m) : 0.f;
  for (int j0 = start + 64; j0 < end; j0 += 64) {
    int j = j0 + lane;
    if (j < end) {
      float e = as_[srcS[j]] + adn;
      e = e > 0.f ? e : 0.2f * e;
      ssum += __expf(e - m);
    }
  }
#pragma unroll
  for (int o = 32; o > 0; o >>= 1) ssum += __shfl_xor(ssum, o);
  float a0 = 0.f, a1 = 0.f, a2 = 0.f, a3 = 0.f;
  const unsigned short* hp = (const unsigned short*)h;
  int c0 = min(deg, 64);
  for (int t = 0; t < c0; ++t) {
    int s = __shfl(sidx, t);
    float ev = __shfl(e0, t);
    float w = __expf(ev - m);
    const ushort4 hv = *(const ushort4*)(hp + (size_t)s * D_HID + lane * 4);
    a0 += us2f(hv.x) * w;
    a1 += us2f(hv.y) * w;
    a2 += us2f(hv.z) * w;
    a3 += us2f(hv.w) * w;
  }
  for (int j = start + 64; j < end; ++j) {   // rare tail
    int s = srcS[j];
    float e = as_[s] + adn;
    e = e > 0.f ? e : 0.2f * e;
    float w = __expf(e - m);
    const ushort4 hv = *(const ushort4*)(hp + (size_t)s * D_HID + lane * 4);
    a0 += us2f(hv.x) * w;
    a1 += us2f(hv.y) * w;
    a2 += us2f(hv.z) * w;
    a3 += us2f(hv.w) * w;
  }
  float inv = 1.f / ssum;
  float4 o4 = {a0 * inv, a1 * inv, a2 * inv, a3 * inv};
  *(float4*)(agg + (size_t)n * D_HID + lane * 4) = o4;
}

// ---------------- batch norm stats (accumulators pre-zeroed by rel_conv) ----------------
__global__ __launch_bounds__(256) void bn_stats_kernel(
    const float* __restrict__ h, float* __restrict__ sums, float* __restrict__ sumsq) {
  int col = threadIdx.x;
  float s = 0.f, q = 0.f;
  for (int r = blockIdx.x; r < N_NODES; r += gridDim.x) {
    float v = h[(size_t)r * D_HID + col];
    s += v; q += v * v;
  }
  atomicAdd(&sums[col], s);
  atomicAdd(&sumsq[col], q);
}

// ---------------- mean pool (node_batch sorted) + b2 + relu ----------------
__global__ __launch_bounds__(256) void pool_kernel(
    const float* __restrict__ h, const float* __restrict__ bias2,
    const int* __restrict__ nb, float* __restrict__ pooled) {
  int col = threadIdx.x;
  float bias = bias2[col];
  int chunk = (N_NODES + gridDim.x - 1) / gridDim.x;
  int r0 = blockIdx.x * chunk;
  int r1 = min(N_NODES, r0 + chunk);
  float acc = 0.f; int cur = -1;
  for (int r = r0; r < r1; ++r) {
    int g = nb[r];
    if (g != cur) {
      if (cur >= 0) atomicAdd(&pooled[(size_t)cur * D_HID + col], acc);
      acc = 0.f; cur = g;
    }
    acc += fmaxf(h[(size_t)r * D_HID + col] + bias, 0.f);
  }
  if (cur >= 0) atomicAdd(&pooled[(size_t)cur * D_HID + col], acc);
}

// ---------------- classifier; per-graph count via binary search on sorted nb ----------------
__global__ __launch_bounds__(256) void clf_kernel(
    const float* __restrict__ pooled, const int* __restrict__ nb,
    const float* __restrict__ claim, const float* __restrict__ clfW,
    const float* __restrict__ clfb, float* __restrict__ out) {
  __shared__ float buf[4];
  __shared__ int cntSh;
  int g = blockIdx.x;
  if (threadIdx.x == 0) {
    int lo = 0, hi = N_NODES;
    while (lo < hi) { int mid = (lo + hi) >> 1; if (nb[mid] < g) lo = mid + 1; else hi = mid; }
    int lb = lo; hi = N_NODES;
    while (lo < hi) { int mid = (lo + hi) >> 1; if (nb[mid] <= g) lo = mid + 1; else hi = mid; }
    cntSh = lo - lb;
  }
  __syncthreads();
  float inv = 1.f / fmaxf((float)cntSh, 1.f);
  float p = 0.f;
  for (int d = threadIdx.x; d < (D_HID + D_IN); d += 256) {
    float w = clfW[d];
    float v = (d < D_HID) ? pooled[(size_t)g * D_HID + d] * inv
                          : claim[(size_t)g * D_IN + (d - D_HID)];
    p += v * w;
  }
  p = blockReduce256(p, buf);
  if (threadIdx.x == 0) out[g] = p + clfb[0];
}

extern "C" void kernel_launch(void* const* d_in, const int* in_sizes, int n_in,
                              void* d_out, int out_size, void* d_ws, size_t ws_size,
                              hipStream_t stream) {
  const float* claim = (const float*)d_in[0];
  const float* x     = (const float*)d_in[1];
  const void*  edge  = d_in[2];
  const void*  nbin  = d_in[3];
  const float* W1    = (const float*)d_in[4];
  const float* as1   = (const float*)d_in[5];
  const float* ad1   = (const float*)d_in[6];
  // d_in[7] = b1: cancels in BatchNorm
  const float* W2    = (const float*)d_in[8];
  const float* as2   = (const float*)d_in[9];
  const float* ad2   = (const float*)d_in[10];
  const float* b2v   = (const float*)d_in[11];
  const float* gamma = (const float*)d_in[12];
  const float* beta  = (const float*)d_in[13];
  const float* clfW  = (const float*)d_in[14];
  const float* clfb  = (const float*)d_in[15];
  float* out = (float*)d_out;

  char* wsb = (char*)d_ws;
  size_t off = 0;
  auto alloc = [&](size_t bytes) -> char* {
    char* p = wsb + off;
    off = (off + bytes + 255) & ~(size_t)255;
    return p;
  };
  int*   flagNZ = (int*)alloc(sizeof(int));
  int*   src32  = (int*)alloc((size_t)N_EDGES * sizeof(int));
  int*   dst32  = (int*)alloc((size_t)N_EDGES * sizeof(int));
  int*   nb32   = (int*)alloc((size_t)N_NODES * sizeof(int));
  int*   deg    = (int*)alloc((size_t)N_NODES * sizeof(int));
  int*   rowptr = (int*)alloc((size_t)(N_NODES + 1) * sizeof(int));
  int*   pos    = (int*)alloc((size_t)N_NODES * sizeof(int));
  int*   incl   = (int*)alloc((size_t)N_NODES * sizeof(int));
  int*   bsums  = (int*)alloc((size_t)SCAN_NB * sizeof(int));
  int*   srcS   = (int*)alloc((size_t)E_TOT * sizeof(int));
  short* W1T    = (short*)alloc((size_t)D_IN * D_HID * sizeof(short));
  short* W2T    = (short*)alloc((size_t)D_HID * D_HID * sizeof(short));
  float* alphas = (float*)alloc((size_t)N_NODES * sizeof(float));
  float* alphad = (float*)alloc((size_t)N_NODES * sizeof(float));
  float* bnsums = (float*)alloc(D_HID * sizeof(float));
  float* bnsq   = (float*)alloc(D_HID * sizeof(float));
  float* pooled = (float*)alloc((size_t)N_GRAPHS * D_HID * sizeof(float));
  float* agg    = (float*)alloc((size_t)N_NODES * D_HID * sizeof(float));
  bf16*  h      = (bf16*) alloc((size_t)N_NODES * D_HID * sizeof(bf16));
  short* Abf    = (short*)alloc((size_t)N_NODES * D_IN * sizeof(short));
  short* A2     = Abf;   // layer-2 bf16 A reuses Abf

  // ---- index normalization + CSR build (no memsets: kernels self-initialize) ----
  detect_idx_kernel<<<1, 256, 0, stream>>>((const int*)edge, flagNZ);
  normalize_idx_kernel<<<(N_EDGES + N_NODES + 255) / 256, 256, 0, stream>>>(
      edge, nbin, flagNZ, src32, dst32, nb32, deg);
  int egrid = (E_TOT + 255) / 256;
  hist_kernel<<<egrid, 256, 0, stream>>>(dst32, deg);
  scan_local_kernel<<<SCAN_NB, 256, 0, stream>>>(deg, incl, bsums);
  scan_add_kernel<<<(N_NODES + 255) / 256, 256, 0, stream>>>(deg, incl, bsums, rowptr, pos);
  scatter_kernel<<<egrid, 256, 0, stream>>>(src32, dst32, pos, srcS);

  // ---- weights -> transposed bf16 (one launch) ----
  convert_wt_kernel<<<(D_IN * D_HID + D_HID * D_HID + 255) / 256, 256, 0, stream>>>(
      W1, W2, W1T, W2T);

  int gemmGrid = ((N_NODES + 127) / 128) * 2;   // 391 m-tiles x 2 n-tiles

  // ---- layer 1 ----
  rel_conv_kernel<<<N_NODES / 4, 256, 0, stream>>>(
      x, claim, nb32, Abf, alphas, alphad, bnsums, bnsq);
  mfma_gemm_bf16_kernel<<<gemmGrid, 256, 0, stream>>>(
      Abf, W1T, as1, ad1, alphas, alphad, h, N_NODES, D_IN);
  gat_agg_kernel<<<N_NODES / 4, 256, 0, stream>>>(rowptr, srcS, alphas, alphad, h, agg);

  bn_stats_kernel<<<256, 256, 0, stream>>>(agg, bnsums, bnsq);

  // ---- layer 2 (BN finalize + scale/shift + ReLU folded into bf16 conversion) ----
  bn_conv_kernel<<<(N_NODES * D_HID / 4 + 255) / 256, 256, 0, stream>>>(
      agg, bnsums, bnsq, gamma, beta, A2, alphas, alphad, pooled);
  mfma_gemm_bf16_kernel<<<gemmGrid, 256, 0, stream>>>(
      A2, W2T, as2, ad2, alphas, alphad, h, N_NODES, D_HID);
  gat_agg_kernel<<<N_NODES / 4, 256, 0, stream>>>(rowptr, srcS, alphas, alphad, h, agg);

  // ---- pool + classifier ----
  pool_kernel<<<256, 256, 0, stream>>>(agg, b2v, nb32, pooled);
  clf_kernel<<<N_GRAPHS, 256, 0, stream>>>(pooled, nb32, claim, clfW, clfb, out);
}